// Round 13
// baseline (1453.859 us; speedup 1.0000x reference)
//
#include <hip/hip_runtime.h>

// ---------------------------------------------------------------------------
// SPADE-style encoder.
// conv3: bf16 MFMA implicit-GEMM, 4 waves = 128px x 128co, wave tile 64x64,
//        3 blocks/CU. R12: tap-level B register double-buffer bf[2][4] —
//        tap t+1's 4 B-loads issue before tap t's 16-MFMA cluster, so
//        L2/L3 latency hides under MFMA (R11 was latency-bound, all pipes
//        ~20%). Chunks processed in static (P=0,P=1) pairs so all register
//        indices fold (R7's lesson: this structure needs acc=64, not 128).
// inorm_stats/apply: short8-vectorized, LDS-reduced stats.
// convT: bf16 MFMA per-parity-class GEMM with coalesced B tiles.
// conv0/conv1/conv2 + their instance-norms still fp32 vector.
// ---------------------------------------------------------------------------

#define B 8

typedef __attribute__((ext_vector_type(8))) short short8;
typedef __attribute__((ext_vector_type(4))) float f32x4;

static __device__ __forceinline__ unsigned short f2bf(float f) {
  union { float f; unsigned u; } v;
  v.f = f;
  unsigned r = v.u + 0x7fffu + ((v.u >> 16) & 1u);
  return (unsigned short)(r >> 16);
}
static __device__ __forceinline__ float bf2f(unsigned short h) {
  union { unsigned u; float f; } v;
  v.u = (unsigned)h << 16;
  return v.f;
}
static __device__ __forceinline__ float tanh_fast(float x) {
  float ax = fabsf(x);
  ax = fminf(ax, 20.f);
  const float e = __expf(-2.f * ax);
  const float t = (1.f - e) / (1.f + e);
  return __builtin_copysignf(t, x);
}

// async 16B global -> LDS (linear dest: wave-uniform base + lane*16)
static __device__ __forceinline__ void gload_lds16(const unsigned short* g,
                                                   unsigned short* l) {
  __builtin_amdgcn_global_load_lds(
      (const __attribute__((address_space(1))) unsigned int*)(const void*)g,
      (__attribute__((address_space(3))) unsigned int*)(void*)l, 16, 0, 0);
}

// ---------------- conv0: 3->32, reflect pad 1, 256x256 ----------------
__global__ __launch_bounds__(256) void conv0_kernel(
    const float* __restrict__ in, const float* __restrict__ w,
    const float* __restrict__ bias, float* __restrict__ out) {
  __shared__ float sw[32 * 27 + 32];
  for (int i = threadIdx.x; i < 32 * 27; i += 256) sw[i] = w[i];
  if (threadIdx.x < 32) sw[32 * 27 + threadIdx.x] = bias[threadIdx.x];
  __syncthreads();
  const int b = blockIdx.y;
  const int p = blockIdx.x * 256 + threadIdx.x;
  const int y = p >> 8, x = p & 255;
  const float* inb = in + (size_t)b * 3 * 65536;
  float v[27];
#pragma unroll
  for (int c = 0; c < 3; ++c) {
#pragma unroll
    for (int ky = 0; ky < 3; ++ky) {
      int iy = y + ky - 1;
      iy = iy < 0 ? -iy : (iy > 255 ? 510 - iy : iy);
#pragma unroll
      for (int kx = 0; kx < 3; ++kx) {
        int ix = x + kx - 1;
        ix = ix < 0 ? -ix : (ix > 255 ? 510 - ix : ix);
        v[c * 9 + ky * 3 + kx] = inb[c * 65536 + iy * 256 + ix];
      }
    }
  }
  float* ob = out + (size_t)b * 32 * 65536 + p;
#pragma unroll
  for (int co = 0; co < 32; ++co) {
    float a = sw[32 * 27 + co];
#pragma unroll
    for (int k = 0; k < 27; ++k) a = fmaf(v[k], sw[co * 27 + k], a);
    ob[(size_t)co * 65536] = a;
  }
}

// ---------------- fused instance-norm + leaky relu (in place, fp32) ----------
__global__ __launch_bounds__(256) void inorm_lrelu_kernel(float* __restrict__ x,
                                                          int HW) {
  const size_t base = (size_t)blockIdx.x * HW;
  float4* p = (float4*)(x + base);
  const int n4 = HW >> 2;
  float s = 0.f, q = 0.f;
  for (int i = threadIdx.x; i < n4; i += 256) {
    float4 v = p[i];
    s += (v.x + v.y) + (v.z + v.w);
    q += (v.x * v.x + v.y * v.y) + (v.z * v.z + v.w * v.w);
  }
  __shared__ float rs[256], rq[256];
  rs[threadIdx.x] = s;
  rq[threadIdx.x] = q;
  __syncthreads();
  for (int st = 128; st > 0; st >>= 1) {
    if (threadIdx.x < st) {
      rs[threadIdx.x] += rs[threadIdx.x + st];
      rq[threadIdx.x] += rq[threadIdx.x + st];
    }
    __syncthreads();
  }
  const float m = rs[0] / (float)HW;
  float var = rq[0] / (float)HW - m * m;
  var = var < 0.f ? 0.f : var;
  const float r = rsqrtf(var + 1e-5f);
  for (int i = threadIdx.x; i < n4; i += 256) {
    float4 v = p[i];
    v.x = (v.x - m) * r; v.x = v.x >= 0.f ? v.x : 0.2f * v.x;
    v.y = (v.y - m) * r; v.y = v.y >= 0.f ? v.y : 0.2f * v.y;
    v.z = (v.z - m) * r; v.z = v.z >= 0.f ? v.z : 0.2f * v.z;
    v.w = (v.w - m) * r; v.w = v.w >= 0.f ? v.w : 0.2f * v.w;
    p[i] = v;
  }
}

// ---------------- 3x3 stride-2 zero-pad-1 conv, 32 co per block ----------------
template <int CIN, int COUT, int HIN>
__global__ __launch_bounds__(256) void conv_s2_kernel(
    const float* __restrict__ in, const float* __restrict__ w,
    const float* __restrict__ bias, float* __restrict__ out) {
  constexpr int HOUT = HIN / 2;
  const int b = blockIdx.z;
  const int co0 = blockIdx.y * 32;
  const int p = blockIdx.x * 256 + threadIdx.x;
  const int oy = p / HOUT, ox = p % HOUT;
  float acc[32];
#pragma unroll
  for (int i = 0; i < 32; ++i) acc[i] = bias[co0 + i];
  const float* inb = in + (size_t)b * CIN * HIN * HIN;
  const int iy0 = 2 * oy - 1, ix0 = 2 * ox - 1;
  for (int ci = 0; ci < CIN; ++ci) {
    float v[9];
    const float* ip = inb + (size_t)ci * HIN * HIN;
#pragma unroll
    for (int ky = 0; ky < 3; ++ky) {
      const int iy = iy0 + ky;
      const bool yok = (unsigned)iy < (unsigned)HIN;
#pragma unroll
      for (int kx = 0; kx < 3; ++kx) {
        const int ix = ix0 + kx;
        const bool ok = yok && ((unsigned)ix < (unsigned)HIN);
        v[ky * 3 + kx] = ok ? ip[iy * HIN + ix] : 0.f;
      }
    }
    const float* wp = w + ((size_t)co0 * CIN + ci) * 9;
#pragma unroll
    for (int co = 0; co < 32; ++co) {
#pragma unroll
      for (int k = 0; k < 9; ++k)
        acc[co] = fmaf(v[k], wp[(size_t)co * CIN * 9 + k], acc[co]);
    }
  }
  float* ob = out + ((size_t)b * COUT + co0) * HOUT * HOUT + p;
#pragma unroll
  for (int co = 0; co < 32; ++co) ob[(size_t)co * HOUT * HOUT] = acc[co];
}

// -------- transpose x2: fp32 [b][128][4096] -> X2p bf16 [b][65][65][128] ----
__global__ __launch_bounds__(256) void transpose_x2_kernel(
    const float* __restrict__ x2, unsigned short* __restrict__ X2p) {
  const int b = blockIdx.y;
  const int p0 = (blockIdx.x & 63) * 64;
  const int ci0 = (blockIdx.x >> 6) * 64;
  __shared__ unsigned short T[64][66];
  const float* src = x2 + (size_t)b * 128 * 4096;
  const int t = threadIdx.x;
#pragma unroll
  for (int r = 0; r < 16; ++r) {
    const int ci_l = r * 4 + (t >> 6);
    const int p_l = t & 63;
    T[ci_l][p_l] = f2bf(src[(size_t)(ci0 + ci_l) * 4096 + p0 + p_l]);
  }
  __syncthreads();
  unsigned short* dst = X2p + (size_t)b * 65 * 65 * 128;
#pragma unroll
  for (int r = 0; r < 2; ++r) {
    const int p_l = r * 32 + (t >> 3);
    const int c0 = (t & 7) * 8;
    union { short8 v; unsigned short u[8]; } pk;
#pragma unroll
    for (int j = 0; j < 8; ++j) pk.u[j] = T[c0 + j][p_l];
    const int p = p0 + p_l;
    const int yy = p >> 6, xx = p & 63;
    *(short8*)(dst + ((size_t)yy * 65 + xx) * 128 + ci0 + c0) = pk.v;
  }
}

// ---------------- zero pad row 64 / col 64 of X2p ----------------
__global__ __launch_bounds__(256) void zpad_x2_kernel(unsigned short* __restrict__ X2p) {
  const int b = blockIdx.x;
  unsigned short* Xb = X2p + (size_t)b * 65 * 65 * 128;
  for (int i = threadIdx.x; i < 129 * 128; i += 256) {
    const int j = i >> 7, ci = i & 127;
    size_t off;
    if (j < 65) off = ((size_t)64 * 65 + j) * 128 + ci;
    else off = ((size_t)(j - 65) * 65 + 64) * 128 + ci;
    Xb[off] = 0;
  }
}

// -------- weight repack (coalesced tiles): wt fp32 [256][128][3][3] ->
// -------- Wtb2 bf16 [9][cot16][c4(4)][lane64][8] ----------------------------
__global__ __launch_bounds__(256) void wtprep_kernel(const float* __restrict__ wt,
                                                     unsigned short* __restrict__ Wtb2) {
  const int i = blockIdx.x * 256 + threadIdx.x;
  if (i >= 9 * 256 * 128) return;
  const int e = i & 7, lane = (i >> 3) & 63, c4 = (i >> 9) & 3;
  const int cot = (i >> 11) & 15, tap = i >> 15;
  const int co = cot * 16 + (lane & 15);
  const int ci = c4 * 32 + (lane >> 4) * 8 + e;
  Wtb2[i] = f2bf(wt[((size_t)co * 128 + ci) * 9 + tap]);
}

// ---------------- convT as bf16 MFMA per-parity-class GEMM ----------------
__global__ __launch_bounds__(256, 3) void convt_mfma_kernel(
    const unsigned short* __restrict__ X2p, const unsigned short* __restrict__ Wtb2,
    const float* __restrict__ bt, unsigned short* __restrict__ Y) {
  const int raw = blockIdx.x;
  const int swz = (raw & 7) * 256 + (raw >> 3);
  const int b = swz >> 8;
  const int rem = swz & 255;
  const int cls = rem >> 6;
  const int sy = rem & 63;
  const int py = cls & 1, px = cls >> 1;

  const int kyA = py ? 0 : 1, kxA = px ? 0 : 1;
  int tk[4], tdy[4], tdx[4];
  int ntaps = 0;
  tk[ntaps] = kyA * 3 + kxA; tdy[ntaps] = 0; tdx[ntaps] = 0; ++ntaps;
  if (px) { tk[ntaps] = kyA * 3 + 2; tdy[ntaps] = 0; tdx[ntaps] = 1; ++ntaps; }
  if (py) { tk[ntaps] = 6 + kxA; tdy[ntaps] = 1; tdx[ntaps] = 0; ++ntaps; }
  if (py && px) { tk[ntaps] = 8; tdy[ntaps] = 1; tdx[ntaps] = 1; ++ntaps; }

  constexpr int CS = 36;
  constexpr int BUFN = 2 * 65 * CS;
  __shared__ unsigned short As2[2 * BUFN];

  const int t = threadIdx.x;
  const int lane = t & 63;
  const int wn = t >> 6;
  const int lg = lane >> 4, lr = lane & 15;
  const int co_w = wn * 64;

  const unsigned short* Xb = X2p + (size_t)b * 65 * 65 * 128;

  int dof0, dof1, dof2;
  const unsigned short *sp0, *sp1, *sp2;
  bool sv2;
  {
    const int i0 = t, i1 = t + 256, i2 = t + 512;
    const int r0 = i0 / 260, c0_ = (i0 % 260) >> 2, h0 = i0 & 3;
    const int r1 = i1 / 260, c1_ = (i1 % 260) >> 2, h1 = i1 & 3;
    sv2 = i2 < 520;
    const int i2c = sv2 ? i2 : 512;
    const int r2 = i2c / 260, c2_ = (i2c % 260) >> 2, h2 = i2c & 3;
    dof0 = (r0 * 65 + c0_) * CS + h0 * 8;
    dof1 = (r1 * 65 + c1_) * CS + h1 * 8;
    dof2 = (r2 * 65 + c2_) * CS + h2 * 8;
    sp0 = Xb + ((size_t)(sy + r0) * 65 + c0_) * 128 + h0 * 8;
    sp1 = Xb + ((size_t)(sy + r1) * 65 + c1_) * 128 + h1 * 8;
    sp2 = Xb + ((size_t)(sy + r2) * 65 + c2_) * 128 + h2 * 8;
  }

  f32x4 acc[4][4];
#pragma unroll
  for (int mt = 0; mt < 4; ++mt)
#pragma unroll
    for (int nt = 0; nt < 4; ++nt) {
      f32x4 z = {0.f, 0.f, 0.f, 0.f};
      acc[mt][nt] = z;
    }

  {
    const short8 a = *(const short8*)sp0;
    const short8 bq = *(const short8*)sp1;
    short8 cq;
    if (sv2) cq = *(const short8*)sp2;
    *(short8*)(As2 + dof0) = a;
    *(short8*)(As2 + dof1) = bq;
    if (sv2) *(short8*)(As2 + dof2) = cq;
  }
  __syncthreads();

  const unsigned short* wlane = Wtb2 + (size_t)lane * 8;

  for (int c8 = 0; c8 < 4; ++c8) {
    short8 n0, n1, n2;
    if (c8 < 3) {
      const int cn = (c8 + 1) * 32;
      n0 = *(const short8*)(sp0 + cn);
      n1 = *(const short8*)(sp1 + cn);
      if (sv2) n2 = *(const short8*)(sp2 + cn);
    }
    const unsigned short* Ab = As2 + (c8 & 1) * BUFN;
    for (int tp = 0; tp < ntaps; ++tp) {
      const int dy = tdy[tp], dx = tdx[tp];
      short8 af[4];
#pragma unroll
      for (int mt = 0; mt < 4; ++mt)
        af[mt] = *(const short8*)(Ab + (dy * 65 + mt * 16 + lr + dx) * CS + lg * 8);
      const unsigned short* wt_ =
          wlane + (size_t)(((tk[tp] * 16 + wn * 4) * 4) + c8) * 512;
#pragma unroll
      for (int nt = 0; nt < 4; ++nt) {
        const short8 bf = *(const short8*)(wt_ + (size_t)nt * (4 * 512));
#pragma unroll
        for (int mt = 0; mt < 4; ++mt)
          acc[mt][nt] = __builtin_amdgcn_mfma_f32_16x16x32_bf16(
              af[mt], bf, acc[mt][nt], 0, 0, 0);
      }
    }
    if (c8 < 3) {
      unsigned short* Db = As2 + ((c8 + 1) & 1) * BUFN;
      *(short8*)(Db + dof0) = n0;
      *(short8*)(Db + dof1) = n1;
      if (sv2) *(short8*)(Db + dof2) = n2;
    }
    __syncthreads();
  }

  const int oy = 2 * sy + py;
  unsigned short* Yb = Y + ((size_t)b * 16384 + (size_t)oy * 128 + px) * 256;
  float bco[4];
#pragma unroll
  for (int nt = 0; nt < 4; ++nt) bco[nt] = bt[co_w + nt * 16 + lr];
#pragma unroll
  for (int mt = 0; mt < 4; ++mt) {
#pragma unroll
    for (int r = 0; r < 4; ++r) {
      const int sx = mt * 16 + lg * 4 + r;
      unsigned short* yp = Yb + (size_t)(2 * sx) * 256 + co_w + lr;
#pragma unroll
      for (int nt = 0; nt < 4; ++nt)
        yp[nt * 16] = f2bf(acc[mt][nt][r] + bco[nt]);
    }
  }
}

// ------- instance-norm stats over pixel-major Y (short8, LDS-reduced) -------
__global__ __launch_bounds__(256) void inorm_stats_kernel(
    const unsigned short* __restrict__ Y, float* __restrict__ ssum,
    float* __restrict__ ssq) {
  const int b = blockIdx.y, sl = blockIdx.x;
  const int t = threadIdx.x;
  const int rg = t >> 5;
  const int c0 = (t & 31) * 8;
  const unsigned short* base = Y + ((size_t)b * 16384 + sl * 256) * 256;
  float s[8], q[8];
#pragma unroll
  for (int j = 0; j < 8; ++j) { s[j] = 0.f; q[j] = 0.f; }
  for (int i = 0; i < 32; ++i) {
    union { short8 v; unsigned short u[8]; } pk;
    pk.v = *(const short8*)(base + (size_t)(rg + i * 8) * 256 + c0);
#pragma unroll
    for (int j = 0; j < 8; ++j) {
      const float v = bf2f(pk.u[j]);
      s[j] += v;
      q[j] += v * v;
    }
  }
  __shared__ float sm[2][8][256];
#pragma unroll
  for (int j = 0; j < 8; ++j) {
    sm[0][rg][c0 + j] = s[j];
    sm[1][rg][c0 + j] = q[j];
  }
  __syncthreads();
  float ts = 0.f, tq = 0.f;
#pragma unroll
  for (int g = 0; g < 8; ++g) {
    ts += sm[0][g][t];
    tq += sm[1][g][t];
  }
  atomicAdd(&ssum[b * 256 + t], ts);
  atomicAdd(&ssq[b * 256 + t], tq);
}

// ------- apply IN + LReLU to Y (short8), write bf16 into Xpad interior -------
__global__ __launch_bounds__(256) void inorm_apply_kernel(
    const unsigned short* __restrict__ Y, const float* __restrict__ ssum,
    const float* __restrict__ ssq, unsigned short* __restrict__ Xpad) {
  const int b = blockIdx.y, sl = blockIdx.x;
  const int t = threadIdx.x;
  const int rg = t >> 5;
  const int c0 = (t & 31) * 8;
  float m[8], r[8];
#pragma unroll
  for (int j = 0; j < 8; ++j) {
    const float mm = ssum[b * 256 + c0 + j] * (1.f / 16384.f);
    float var = ssq[b * 256 + c0 + j] * (1.f / 16384.f) - mm * mm;
    var = var < 0.f ? 0.f : var;
    m[j] = mm;
    r[j] = rsqrtf(var + 1e-5f);
  }
  const unsigned short* base = Y + ((size_t)b * 16384 + sl * 256) * 256;
  unsigned short* dstb = Xpad + (size_t)b * 130 * 130 * 256;
  for (int i = 0; i < 32; ++i) {
    const int row = sl * 256 + rg + i * 8;
    const int yy = row >> 7, xx = row & 127;
    union { short8 v; unsigned short u[8]; } pk;
    pk.v = *(const short8*)(base + (size_t)(rg + i * 8) * 256 + c0);
#pragma unroll
    for (int j = 0; j < 8; ++j) {
      float v = bf2f(pk.u[j]);
      v = (v - m[j]) * r[j];
      v = v >= 0.f ? v : 0.2f * v;
      pk.u[j] = f2bf(v);
    }
    *(short8*)(dstb + ((size_t)(yy + 1) * 130 + (xx + 1)) * 256 + c0) = pk.v;
  }
}

// ---------------- reflect borders of Xpad: rows then cols ----------------
__global__ __launch_bounds__(256) void pad_rows_kernel(unsigned short* __restrict__ Xp) {
  const int b = blockIdx.x >> 1, side = blockIdx.x & 1;
  unsigned short* Xb = Xp + (size_t)b * 130 * 130 * 256;
  const int dr = side ? 129 : 0, sr = side ? 127 : 2;
  for (int i = threadIdx.x; i < 4096; i += 256) {
    const int c = 1 + (i >> 5), o = (i & 31) * 8;
    *(short8*)(Xb + ((size_t)dr * 130 + c) * 256 + o) =
        *(const short8*)(Xb + ((size_t)sr * 130 + c) * 256 + o);
  }
}
__global__ __launch_bounds__(256) void pad_cols_kernel(unsigned short* __restrict__ Xp) {
  const int b = blockIdx.x >> 1, side = blockIdx.x & 1;
  unsigned short* Xb = Xp + (size_t)b * 130 * 130 * 256;
  const int dc = side ? 129 : 0, sc = side ? 127 : 2;
  for (int i = threadIdx.x; i < 130 * 32; i += 256) {
    const int r = i >> 5, o = (i & 31) * 8;
    *(short8*)(Xb + ((size_t)r * 130 + dc) * 256 + o) =
        *(const short8*)(Xb + ((size_t)r * 130 + sc) * 256 + o);
  }
}

// ------ weight repack (coalesced tiles): w3 fp32 [512][256][9] ->
// ------ Wb2 bf16 [9][cot32][c8(8)][lane64][8]; co=cot*16+lr, ci=c8*32+lg*8+e
__global__ __launch_bounds__(256) void wprep_kernel(const float* __restrict__ w3,
                                                    unsigned short* __restrict__ Wb2) {
  const int i = blockIdx.x * 256 + threadIdx.x;
  if (i >= 9 * 512 * 256) return;
  const int e = i & 7, lane = (i >> 3) & 63, c8 = (i >> 9) & 7;
  const int cot = (i >> 12) & 31, tap = i >> 17;
  const int co = cot * 16 + (lane & 15);
  const int ci = c8 * 32 + (lane >> 4) * 8 + e;
  Wb2[i] = f2bf(w3[((size_t)co * 256 + ci) * 9 + tap]);
}

// ---------------- label extraction + counts from one-hot segmap ----------------
__global__ __launch_bounds__(256) void label_kernel(
    const float* __restrict__ segmap, int* __restrict__ labels,
    float* __restrict__ cnt) {
  const int b = blockIdx.y;
  const int p = blockIdx.x * 256 + threadIdx.x;
  const int i = p >> 7, j = p & 127;
  const float* sp = segmap + (size_t)b * 19 * 65536 + (2 * i) * 256 + 2 * j;
  int lab = 0;
#pragma unroll
  for (int s = 0; s < 19; ++s)
    if (sp[(size_t)s * 65536] != 0.f) lab = s;
  labels[b * 16384 + p] = lab;
  atomicAdd(&cnt[b * 19 + lab], 1.0f);
}

// ---------------- conv3: bf16 MFMA implicit GEMM + tanh + region pool --------
// Block = 256 threads (4 waves) = one image row (128 px) x 128 co.
// Wave grid 2Mx2N, wave tile 64px x 64co, acc 4x4 f32x4 = 64 regs ->
// 3 waves/SIMD, 3 blocks/CU. A-halo async global_load_lds + XOR pair.
// R12: tap-level B register double-buffer bf[2][4]: tap t+1's B-loads
// issue before tap t's MFMA cluster; tap 8 prefetches next chunk's tap 0.
// Chunks run in static (P=0,P=1) pairs so all bf[] indices fold.
__global__ __launch_bounds__(256, 3) void conv3_mfma_pool_kernel(
    const unsigned short* __restrict__ Xpad, const unsigned short* __restrict__ Wb2,
    const float* __restrict__ bias, const int* __restrict__ labels,
    float* __restrict__ sums) {
  // XCD swizzle: 4096 = 8 XCDs x 512 -> one batch per XCD
  const int raw = blockIdx.x;
  const int swz = (raw & 7) * 512 + (raw >> 3);
  const int b = swz >> 9;
  const int rem = swz & 511;
  const int y = rem >> 2;   // image row
  const int coq = rem & 3;  // co quarter (128 co)

  constexpr int SLOTS = 1600;  // 1560 used (3*130*4) + tail pad
  __shared__ unsigned short Asw[2 * SLOTS * 8];  // 51.2 KB
  float* lsum = (float*)Asw;                     // epilogue reuse (9.7 KB)

  const int t = threadIdx.x;
  const int lane = t & 63;
  const int wave = t >> 6;     // 0..3
  const int wm = wave >> 1;    // 0..1: M group (64 px)
  const int wn = wave & 1;     // 0..1: N group (64 co)
  const int lg = lane >> 4, lr = lane & 15;
  const int co_w = coq * 128 + wn * 64;

  const unsigned short* Xb = Xpad + (size_t)b * 130 * 130 * 256;

  // per-thread global sources: slots t+k*256 (k=0..5) + tail (wave0, lane<24)
  // slot s = E*4 + hs (E = r*130+c); stored quarter h = hs ^ ((E>>1)&3)
  const unsigned short* sp[7];
  {
#pragma unroll
    for (int k = 0; k < 7; ++k) {
      int s;
      if (k < 6) s = t + k * 256;
      else s = (t < 24) ? (1536 + t) : 1536;
      const int r = s / 520, rm = s % 520, c = rm >> 2, hs = rm & 3;
      const int E = r * 130 + c;
      const int h = hs ^ ((E >> 1) & 3);
      sp[k] = Xb + ((size_t)(y + r) * 130 + c) * 256 + h * 8;
    }
  }

  f32x4 acc[4][4];
#pragma unroll
  for (int mt = 0; mt < 4; ++mt)
#pragma unroll
    for (int nt = 0; nt < 4; ++nt) {
      f32x4 z = {0.f, 0.f, 0.f, 0.f};
      acc[mt][nt] = z;
    }

  const unsigned short* wlane = Wb2 + (size_t)lane * 8;
// B-fragment base for (tap, c8) at this thread's (coq, wn):
#define WADDR(TAP, C8)                                                       \
  (wlane + (size_t)((((TAP) * 32 + coq * 8 + wn * 4) * 8) + (C8)) * 512)

  const int wslot = wave * 64;
#define STAGE(bufSel, off)                                                   \
  {                                                                          \
    unsigned short* base_ = Asw + (bufSel) * (SLOTS * 8);                    \
    gload_lds16(sp[0] + (off), base_ + (size_t)wslot * 8);                   \
    gload_lds16(sp[1] + (off), base_ + (size_t)(wslot + 256) * 8);           \
    gload_lds16(sp[2] + (off), base_ + (size_t)(wslot + 512) * 8);           \
    gload_lds16(sp[3] + (off), base_ + (size_t)(wslot + 768) * 8);           \
    gload_lds16(sp[4] + (off), base_ + (size_t)(wslot + 1024) * 8);          \
    gload_lds16(sp[5] + (off), base_ + (size_t)(wslot + 1280) * 8);          \
    if (wave == 0 && lane < 24)                                              \
      gload_lds16(sp[6] + (off), base_ + (size_t)1536 * 8);                  \
  }

  short8 bf[2][4];
  STAGE(0, 0)
  // prefetch B for (chunk 0, tap 0) into bf[0]
  {
    const unsigned short* w0_ = WADDR(0, 0);
#pragma unroll
    for (int nt = 0; nt < 4; ++nt)
      bf[0][nt] = *(const short8*)(w0_ + (size_t)nt * (8 * 512));
  }
  __syncthreads();

// One 32-ci chunk. P (literal 0/1) = which bf half holds tap0's B.
// tap t consumes bf[(t+P)&1]; issues tap t+1's B into bf[(t+1+P)&1];
// tap 8 prefetches next chunk's tap0 into bf[(P+1)&1] (9 odd -> P flips).
#define CHUNK(C8, P)                                                         \
  {                                                                          \
    const int c8_ = (C8);                                                    \
    if (c8_ < 7) STAGE((c8_ + 1) & 1, (c8_ + 1) * 32)                        \
    const unsigned short* Ab = Asw + (c8_ & 1) * (SLOTS * 8);                \
    _Pragma("unroll")                                                        \
    for (int tap = 0; tap < 9; ++tap) {                                      \
      const int cur_ = (tap + (P)) & 1;                                      \
      const int nxt_ = cur_ ^ 1;                                             \
      if (tap < 8) {                                                         \
        const unsigned short* wn_ = WADDR(tap + 1, c8_);                     \
        _Pragma("unroll")                                                    \
        for (int nt = 0; nt < 4; ++nt)                                       \
          bf[nxt_][nt] = *(const short8*)(wn_ + (size_t)nt * (8 * 512));     \
      } else if (c8_ < 7) {                                                  \
        const unsigned short* wn_ = WADDR(0, c8_ + 1);                       \
        _Pragma("unroll")                                                    \
        for (int nt = 0; nt < 4; ++nt)                                       \
          bf[nxt_][nt] = *(const short8*)(wn_ + (size_t)nt * (8 * 512));     \
      }                                                                      \
      const int ky_ = tap / 3, kx_ = tap % 3;                                \
      short8 af[4];                                                          \
      _Pragma("unroll")                                                      \
      for (int mt = 0; mt < 4; ++mt) {                                       \
        const int E = ky_ * 130 + wm * 64 + mt * 16 + lr + kx_;              \
        const int hh = lg ^ ((E >> 1) & 3);                                  \
        af[mt] = *(const short8*)(Ab + (size_t)E * 32 + hh * 8);             \
      }                                                                      \
      _Pragma("unroll")                                                      \
      for (int nt = 0; nt < 4; ++nt) {                                       \
        _Pragma("unroll")                                                    \
        for (int mt = 0; mt < 4; ++mt)                                       \
          acc[mt][nt] = __builtin_amdgcn_mfma_f32_16x16x32_bf16(             \
              af[mt], bf[cur_][nt], acc[mt][nt], 0, 0, 0);                   \
      }                                                                      \
    }                                                                        \
    __syncthreads();                                                         \
  }

  for (int it = 0; it < 4; ++it) {
    CHUNK(it * 2, 0)
    CHUNK(it * 2 + 1, 1)
  }
#undef CHUNK
#undef STAGE
#undef WADDR

  // epilogue: staging LDS dead -> zero lsum in same space
  for (int i = t; i < 19 * 128; i += 256) lsum[i] = 0.f;
  __syncthreads();

  const int* labp = labels + b * 16384 + y * 128;
  float bco[4];
#pragma unroll
  for (int nt = 0; nt < 4; ++nt) bco[nt] = bias[co_w + nt * 16 + lr];
#pragma unroll
  for (int mt = 0; mt < 4; ++mt) {
#pragma unroll
    for (int r = 0; r < 4; ++r) {
      const int lab = labp[wm * 64 + mt * 16 + lg * 4 + r];
#pragma unroll
      for (int nt = 0; nt < 4; ++nt) {
        const float v = tanh_fast(acc[mt][nt][r] + bco[nt]);
        atomicAdd(&lsum[lab * 128 + wn * 64 + nt * 16 + lr], v);
      }
    }
  }
  __syncthreads();
  for (int i = t; i < 19 * 128; i += 256) {
    const float v = lsum[i];
    if (v != 0.f) {
      const int sI = i >> 7, c = i & 127;
      atomicAdd(&sums[((size_t)b * 19 + sI) * 512 + coq * 128 + c], v);
    }
  }
}

// ---------------- finalize: out = cnt>0 ? sums/max(cnt,1) : 0 ----------------
__global__ __launch_bounds__(256) void finalize_kernel(
    const float* __restrict__ sums, const float* __restrict__ cnt,
    float* __restrict__ out) {
  const int i = blockIdx.x * 256 + threadIdx.x;
  if (i >= B * 19 * 512) return;
  const int bs = i >> 9;
  const float c = cnt[bs];
  out[i] = c > 0.f ? sums[i] / fmaxf(c, 1.f) : 0.f;
}

// ---------------------------------------------------------------------------
extern "C" void kernel_launch(void* const* d_in, const int* in_sizes, int n_in,
                              void* d_out, int out_size, void* d_ws,
                              size_t ws_size, hipStream_t stream) {
  const float* input = (const float*)d_in[0];
  const float* segmap = (const float*)d_in[1];
  const float* w0 = (const float*)d_in[2];
  const float* b0 = (const float*)d_in[3];
  const float* w1 = (const float*)d_in[4];
  const float* b1 = (const float*)d_in[5];
  const float* w2 = (const float*)d_in[6];
  const float* b2 = (const float*)d_in[7];
  const float* wt = (const float*)d_in[8];
  const float* bt = (const float*)d_in[9];
  const float* w3 = (const float*)d_in[10];
  const float* b3 = (const float*)d_in[11];
  float* out = (float*)d_out;

  float* ws = (float*)d_ws;
  float* x0 = ws;                                    // 16,777,216 f
  float* x1 = x0 + 16777216;                         //  8,388,608 f
  float* x2 = x1 + 8388608;                          //  4,194,304 f
  unsigned short* X2p = (unsigned short*)(x2 + 4194304);  // 4,326,400 us
  unsigned short* Y = X2p + 4326400;                 // 33,554,432 us
  float* sums = (float*)(Y + 33554432);              //     77,824 f
  float* cnt = sums + 77824;                         //        152 f
  float* ssum = cnt + 152;                           //      2,048 f
  float* ssq = ssum + 2048;                          //      2,048 f
  int* labels = (int*)(ssq + 2048);                  //    131,072 i
  unsigned short* Wb2 = (unsigned short*)(labels + 131072);  // 1,179,648 us
  unsigned short* Wtb2 = Wb2 + 1179648;              //    294,912 us
  unsigned short* Xpad = (unsigned short*)ws;        // 69.2MB over x0+x1 (dead)

  hipMemsetAsync(sums, 0, (77824 + 152 + 2048 + 2048) * sizeof(float), stream);

  wprep_kernel<<<dim3((9 * 512 * 256 + 255) / 256), 256, 0, stream>>>(w3, Wb2);
  wtprep_kernel<<<dim3((9 * 256 * 128 + 255) / 256), 256, 0, stream>>>(wt, Wtb2);
  conv0_kernel<<<dim3(256, B), 256, 0, stream>>>(input, w0, b0, x0);
  inorm_lrelu_kernel<<<dim3(B * 32), 256, 0, stream>>>(x0, 65536);
  conv_s2_kernel<32, 64, 256><<<dim3(64, 2, B), 256, 0, stream>>>(x0, w1, b1, x1);
  inorm_lrelu_kernel<<<dim3(B * 64), 256, 0, stream>>>(x1, 16384);
  conv_s2_kernel<64, 128, 128><<<dim3(16, 4, B), 256, 0, stream>>>(x1, w2, b2, x2);
  inorm_lrelu_kernel<<<dim3(B * 128), 256, 0, stream>>>(x2, 4096);
  transpose_x2_kernel<<<dim3(128, B), 256, 0, stream>>>(x2, X2p);
  zpad_x2_kernel<<<dim3(B), 256, 0, stream>>>(X2p);
  convt_mfma_kernel<<<dim3(2048), 256, 0, stream>>>(X2p, Wtb2, bt, Y);
  inorm_stats_kernel<<<dim3(64, B), 256, 0, stream>>>(Y, ssum, ssq);
  inorm_apply_kernel<<<dim3(64, B), 256, 0, stream>>>(Y, ssum, ssq, Xpad);
  pad_rows_kernel<<<dim3(2 * B), 256, 0, stream>>>(Xpad);
  pad_cols_kernel<<<dim3(2 * B), 256, 0, stream>>>(Xpad);
  label_kernel<<<dim3(64, B), 256, 0, stream>>>(segmap, labels, cnt);
  conv3_mfma_pool_kernel<<<dim3(4096), 256, 0, stream>>>(Xpad, Wb2, b3, labels, sums);
  finalize_kernel<<<dim3((B * 19 * 512 + 255) / 256), 256, 0, stream>>>(sums, cnt, out);
}

// Round 14
// 961.770 us; speedup vs baseline: 1.5116x; 1.5116x over previous
//
#include <hip/hip_runtime.h>

// ---------------------------------------------------------------------------
// SPADE-style encoder — all four big convs now bf16 MFMA implicit-GEMM.
// conv3: R11 structure (4 waves, 128px x 128co, wave tile 64x64, 3 blocks/CU,
//        async global_load_lds A-halo + XOR src/read pair, coalesced B).
//        R12's tap-level reg double-buffer REVERTED (scratch spill, 2nd time).
// conv1/conv2 (R13): same single-stage halo MFMA template; inputs transposed
//        to pixel-major bf16 (Xp0/Xp1, zero-padded borders); bias added in
//        epilogue; IN+LReLU kernels unchanged (fp32 channel-major).
// convT: bf16 MFMA per-parity-class GEMM with coalesced B tiles.
// ---------------------------------------------------------------------------

#define B 8

typedef __attribute__((ext_vector_type(8))) short short8;
typedef __attribute__((ext_vector_type(4))) float f32x4;

static __device__ __forceinline__ unsigned short f2bf(float f) {
  union { float f; unsigned u; } v;
  v.f = f;
  unsigned r = v.u + 0x7fffu + ((v.u >> 16) & 1u);
  return (unsigned short)(r >> 16);
}
static __device__ __forceinline__ float bf2f(unsigned short h) {
  union { unsigned u; float f; } v;
  v.u = (unsigned)h << 16;
  return v.f;
}
static __device__ __forceinline__ float tanh_fast(float x) {
  float ax = fabsf(x);
  ax = fminf(ax, 20.f);
  const float e = __expf(-2.f * ax);
  const float t = (1.f - e) / (1.f + e);
  return __builtin_copysignf(t, x);
}

// async 16B global -> LDS (dest is wave-uniform base; HW adds lane*16)
static __device__ __forceinline__ void gload_lds16(const unsigned short* g,
                                                   unsigned short* l) {
  __builtin_amdgcn_global_load_lds(
      (const __attribute__((address_space(1))) unsigned int*)(const void*)g,
      (__attribute__((address_space(3))) unsigned int*)(void*)l, 16, 0, 0);
}

// ---------------- conv0: 3->32, reflect pad 1, 256x256 (fp32) ----------------
__global__ __launch_bounds__(256) void conv0_kernel(
    const float* __restrict__ in, const float* __restrict__ w,
    const float* __restrict__ bias, float* __restrict__ out) {
  __shared__ float sw[32 * 27 + 32];
  for (int i = threadIdx.x; i < 32 * 27; i += 256) sw[i] = w[i];
  if (threadIdx.x < 32) sw[32 * 27 + threadIdx.x] = bias[threadIdx.x];
  __syncthreads();
  const int b = blockIdx.y;
  const int p = blockIdx.x * 256 + threadIdx.x;
  const int y = p >> 8, x = p & 255;
  const float* inb = in + (size_t)b * 3 * 65536;
  float v[27];
#pragma unroll
  for (int c = 0; c < 3; ++c) {
#pragma unroll
    for (int ky = 0; ky < 3; ++ky) {
      int iy = y + ky - 1;
      iy = iy < 0 ? -iy : (iy > 255 ? 510 - iy : iy);
#pragma unroll
      for (int kx = 0; kx < 3; ++kx) {
        int ix = x + kx - 1;
        ix = ix < 0 ? -ix : (ix > 255 ? 510 - ix : ix);
        v[c * 9 + ky * 3 + kx] = inb[c * 65536 + iy * 256 + ix];
      }
    }
  }
  float* ob = out + (size_t)b * 32 * 65536 + p;
#pragma unroll
  for (int co = 0; co < 32; ++co) {
    float a = sw[32 * 27 + co];
#pragma unroll
    for (int k = 0; k < 27; ++k) a = fmaf(v[k], sw[co * 27 + k], a);
    ob[(size_t)co * 65536] = a;
  }
}

// ---------------- fused instance-norm + leaky relu (in place, fp32) ----------
__global__ __launch_bounds__(256) void inorm_lrelu_kernel(float* __restrict__ x,
                                                          int HW) {
  const size_t base = (size_t)blockIdx.x * HW;
  float4* p = (float4*)(x + base);
  const int n4 = HW >> 2;
  float s = 0.f, q = 0.f;
  for (int i = threadIdx.x; i < n4; i += 256) {
    float4 v = p[i];
    s += (v.x + v.y) + (v.z + v.w);
    q += (v.x * v.x + v.y * v.y) + (v.z * v.z + v.w * v.w);
  }
  __shared__ float rs[256], rq[256];
  rs[threadIdx.x] = s;
  rq[threadIdx.x] = q;
  __syncthreads();
  for (int st = 128; st > 0; st >>= 1) {
    if (threadIdx.x < st) {
      rs[threadIdx.x] += rs[threadIdx.x + st];
      rq[threadIdx.x] += rq[threadIdx.x + st];
    }
    __syncthreads();
  }
  const float m = rs[0] / (float)HW;
  float var = rq[0] / (float)HW - m * m;
  var = var < 0.f ? 0.f : var;
  const float r = rsqrtf(var + 1e-5f);
  for (int i = threadIdx.x; i < n4; i += 256) {
    float4 v = p[i];
    v.x = (v.x - m) * r; v.x = v.x >= 0.f ? v.x : 0.2f * v.x;
    v.y = (v.y - m) * r; v.y = v.y >= 0.f ? v.y : 0.2f * v.y;
    v.z = (v.z - m) * r; v.z = v.z >= 0.f ? v.z : 0.2f * v.z;
    v.w = (v.w - m) * r; v.w = v.w >= 0.f ? v.w : 0.2f * v.w;
    p[i] = v;
  }
}

// ---- transpose x0: fp32 [b][32][65536] -> Xp0 bf16 [b][258][258][32] int. ---
__global__ __launch_bounds__(256) void transpose_x0_kernel(
    const float* __restrict__ x0, unsigned short* __restrict__ Xp0) {
  const int b = blockIdx.y;
  const int p0 = blockIdx.x * 64;  // 1024 px tiles
  __shared__ unsigned short T[32][66];
  const float* src = x0 + (size_t)b * 32 * 65536;
  const int t = threadIdx.x;
#pragma unroll
  for (int r = 0; r < 8; ++r) {
    const int ci_l = r * 4 + (t >> 6);
    const int p_l = t & 63;
    T[ci_l][p_l] = f2bf(src[(size_t)ci_l * 65536 + p0 + p_l]);
  }
  __syncthreads();
  unsigned short* dst = Xp0 + (size_t)b * 258 * 258 * 32;
  const int p_l = t >> 2;
  const int c0 = (t & 3) * 8;
  union { short8 v; unsigned short u[8]; } pk;
#pragma unroll
  for (int j = 0; j < 8; ++j) pk.u[j] = T[c0 + j][p_l];
  const int p = p0 + p_l;
  const int yy = p >> 8, xx = p & 255;
  *(short8*)(dst + ((size_t)(yy + 1) * 258 + (xx + 1)) * 32 + c0) = pk.v;
}

// ---------------- zero row 0 / col 0 of Xp0 ----------------
__global__ __launch_bounds__(256) void zpad0_kernel(unsigned short* __restrict__ Xp0) {
  const int b = blockIdx.x;
  unsigned short* Xb = Xp0 + (size_t)b * 258 * 258 * 32;
  const short8 z = {0, 0, 0, 0, 0, 0, 0, 0};
  for (int i = threadIdx.x; i < 258 * 4; i += 256) {
    const int c = i >> 2, q = (i & 3) * 8;
    *(short8*)(Xb + ((size_t)0 * 258 + c) * 32 + q) = z;      // row 0
    *(short8*)(Xb + ((size_t)c * 258 + 0) * 32 + q) = z;      // col 0
  }
}

// ---- w1 repack: [64][32][3][3] fp32 -> w1b bf16 [9][cot4][lane64][8] ----
__global__ __launch_bounds__(256) void w1prep_kernel(const float* __restrict__ w1,
                                                     unsigned short* __restrict__ w1b) {
  const int i = blockIdx.x * 256 + threadIdx.x;
  if (i >= 9 * 64 * 32) return;
  const int e = i & 7, lane = (i >> 3) & 63, cot = (i >> 9) & 3, tap = i >> 11;
  const int co = cot * 16 + (lane & 15);
  const int ci = (lane >> 4) * 8 + e;
  w1b[i] = f2bf(w1[((size_t)co * 32 + ci) * 9 + tap]);
}

// ---------------- conv1: 32->64 stride-2 MFMA; out x1 fp32 ch-major ----------
// Block = out row oy (128 px) x 64 co; 4 waves 2Mx2N, wave tile 64px x 32co.
// A: single-stage 3x257x32 halo via gload_lds, XOR pair h=hs^((c>>1)&3).
__global__ __launch_bounds__(256, 3) void conv1_mfma_kernel(
    const unsigned short* __restrict__ Xp0, const unsigned short* __restrict__ w1b,
    const float* __restrict__ b1, float* __restrict__ x1) {
  const int raw = blockIdx.x;  // 1024 = 8 XCD x 128
  const int swz = (raw & 7) * 128 + (raw >> 3);
  const int b = swz >> 7;
  const int oy = swz & 127;

  __shared__ unsigned short Asw1[3084 * 8];  // 48.2 KB

  const int t = threadIdx.x;
  const int lane = t & 63;
  const int wave = t >> 6;
  const int wm = wave >> 1, wn = wave & 1;
  const int lg = lane >> 4, lr = lane & 15;
  const int wslot = wave * 64;

  const unsigned short* Xb = Xp0 + (size_t)b * 258 * 258 * 32;

  // stage: slots s = r*1028 + c*4 + hs (r<3, c<257, hs<4); h = hs^((c>>1)&3)
#pragma unroll
  for (int k = 0; k < 13; ++k) {
    int s;
    bool act = true;
    if (k < 12) s = t + k * 256;
    else { s = 3072 + lane; act = (wave == 0 && lane < 12); }
    const int r = s / 1028, rm = s % 1028, c = rm >> 2, hs = rm & 3;
    const int h = hs ^ ((c >> 1) & 3);
    const unsigned short* gsrc = Xb + ((size_t)(2 * oy + r) * 258 + c) * 32 + h * 8;
    unsigned short* ldst = (k < 12) ? (Asw1 + (size_t)(k * 256 + wslot) * 8)
                                    : (Asw1 + (size_t)3072 * 8);
    if (act) gload_lds16(gsrc, ldst);
  }

  f32x4 acc[4][2];
#pragma unroll
  for (int mt = 0; mt < 4; ++mt)
#pragma unroll
    for (int nt = 0; nt < 2; ++nt) {
      f32x4 z = {0.f, 0.f, 0.f, 0.f};
      acc[mt][nt] = z;
    }
  __syncthreads();

  const unsigned short* w1l = w1b + (size_t)lane * 8;
#pragma unroll
  for (int tap = 0; tap < 9; ++tap) {
    const int ky = tap / 3, kx = tap % 3;
    short8 bf[2];
#pragma unroll
    for (int nt = 0; nt < 2; ++nt)
      bf[nt] = *(const short8*)(w1l + (size_t)(tap * 4 + wn * 2 + nt) * 512);
    short8 af[4];
#pragma unroll
    for (int mt = 0; mt < 4; ++mt) {
      const int c = 2 * (wm * 64 + mt * 16 + lr) + kx;
      const int hh = lg ^ ((c >> 1) & 3);
      af[mt] = *(const short8*)(Asw1 + (size_t)(ky * 1028 + c * 4 + hh) * 8);
    }
#pragma unroll
    for (int nt = 0; nt < 2; ++nt)
#pragma unroll
      for (int mt = 0; mt < 4; ++mt)
        acc[mt][nt] = __builtin_amdgcn_mfma_f32_16x16x32_bf16(
            af[mt], bf[nt], acc[mt][nt], 0, 0, 0);
  }

  float b1v[2];
#pragma unroll
  for (int nt = 0; nt < 2; ++nt) b1v[nt] = b1[wn * 32 + nt * 16 + lr];
#pragma unroll
  for (int mt = 0; mt < 4; ++mt) {
#pragma unroll
    for (int nt = 0; nt < 2; ++nt) {
      const int px = wm * 64 + mt * 16 + lg * 4;
      const int co = wn * 32 + nt * 16 + lr;
      float4 v;
      v.x = acc[mt][nt][0] + b1v[nt];
      v.y = acc[mt][nt][1] + b1v[nt];
      v.z = acc[mt][nt][2] + b1v[nt];
      v.w = acc[mt][nt][3] + b1v[nt];
      *(float4*)(x1 + ((size_t)(b * 64 + co)) * 16384 + oy * 128 + px) = v;
    }
  }
}

// ---- transpose x1: fp32 [b][64][16384] -> Xp1 bf16 [b][130][130][64] int. ---
__global__ __launch_bounds__(256) void transpose_x1_kernel(
    const float* __restrict__ x1, unsigned short* __restrict__ Xp1) {
  const int b = blockIdx.y;
  const int p0 = blockIdx.x * 64;  // 256 px tiles
  __shared__ unsigned short T[64][66];
  const float* src = x1 + (size_t)b * 64 * 16384;
  const int t = threadIdx.x;
#pragma unroll
  for (int r = 0; r < 16; ++r) {
    const int ci_l = r * 4 + (t >> 6);
    const int p_l = t & 63;
    T[ci_l][p_l] = f2bf(src[(size_t)ci_l * 16384 + p0 + p_l]);
  }
  __syncthreads();
  unsigned short* dst = Xp1 + (size_t)b * 130 * 130 * 64;
#pragma unroll
  for (int r = 0; r < 2; ++r) {
    const int p_l = r * 32 + (t >> 3);
    const int c0 = (t & 7) * 8;
    union { short8 v; unsigned short u[8]; } pk;
#pragma unroll
    for (int j = 0; j < 8; ++j) pk.u[j] = T[c0 + j][p_l];
    const int p = p0 + p_l;
    const int yy = p >> 7, xx = p & 127;
    *(short8*)(dst + ((size_t)(yy + 1) * 130 + (xx + 1)) * 64 + c0) = pk.v;
  }
}

// ---------------- zero row 0 / col 0 of Xp1 ----------------
__global__ __launch_bounds__(256) void zpad1_kernel(unsigned short* __restrict__ Xp1) {
  const int b = blockIdx.x;
  unsigned short* Xb = Xp1 + (size_t)b * 130 * 130 * 64;
  const short8 z = {0, 0, 0, 0, 0, 0, 0, 0};
  for (int i = threadIdx.x; i < 130 * 8; i += 256) {
    const int c = i >> 3, q = (i & 7) * 8;
    *(short8*)(Xb + ((size_t)0 * 130 + c) * 64 + q) = z;
    *(short8*)(Xb + ((size_t)c * 130 + 0) * 64 + q) = z;
  }
}

// ---- w2 repack: [128][64][3][3] fp32 -> w2b bf16 [9][cot8][cc2][lane64][8] --
__global__ __launch_bounds__(256) void w2prep_kernel(const float* __restrict__ w2,
                                                     unsigned short* __restrict__ w2b) {
  const int i = blockIdx.x * 256 + threadIdx.x;
  if (i >= 9 * 128 * 64) return;
  const int e = i & 7, lane = (i >> 3) & 63, cc = (i >> 9) & 1;
  const int cot = (i >> 10) & 7, tap = i >> 13;
  const int co = cot * 16 + (lane & 15);
  const int ci = cc * 32 + (lane >> 4) * 8 + e;
  w2b[i] = f2bf(w2[((size_t)co * 64 + ci) * 9 + tap]);
}

// ---------------- conv2: 64->128 stride-2 MFMA; out x2 fp32 ch-major ---------
// Block = out row oy (64 px) x 128 co; 4 waves 2Mx2N, wave tile 32px x 64co.
// A: single-stage 3x129x64 halo; h = hs^((c>>1)&7), hs over 8 ci-halves.
__global__ __launch_bounds__(256, 3) void conv2_mfma_kernel(
    const unsigned short* __restrict__ Xp1, const unsigned short* __restrict__ w2b,
    const float* __restrict__ b2, float* __restrict__ x2) {
  const int raw = blockIdx.x;  // 512 = 8 XCD x 64
  const int swz = (raw & 7) * 64 + (raw >> 3);
  const int b = swz >> 6;
  const int oy = swz & 63;

  __shared__ unsigned short Asw2[3096 * 8];  // 48.4 KB

  const int t = threadIdx.x;
  const int lane = t & 63;
  const int wave = t >> 6;
  const int wm = wave >> 1, wn = wave & 1;
  const int lg = lane >> 4, lr = lane & 15;
  const int wslot = wave * 64;

  const unsigned short* Xb = Xp1 + (size_t)b * 130 * 130 * 64;

  // stage: slots s = r*1032 + c*8 + hs (r<3, c<129, hs<8); h = hs^((c>>1)&7)
#pragma unroll
  for (int k = 0; k < 13; ++k) {
    int s;
    bool act = true;
    if (k < 12) s = t + k * 256;
    else { s = 3072 + lane; act = (wave == 0 && lane < 24); }
    const int r = s / 1032, rm = s % 1032, c = rm >> 3, hs = rm & 7;
    const int h = hs ^ ((c >> 1) & 7);
    const unsigned short* gsrc = Xb + ((size_t)(2 * oy + r) * 130 + c) * 64 + h * 8;
    unsigned short* ldst = (k < 12) ? (Asw2 + (size_t)(k * 256 + wslot) * 8)
                                    : (Asw2 + (size_t)3072 * 8);
    if (act) gload_lds16(gsrc, ldst);
  }

  f32x4 acc[2][4];
#pragma unroll
  for (int mt = 0; mt < 2; ++mt)
#pragma unroll
    for (int nt = 0; nt < 4; ++nt) {
      f32x4 z = {0.f, 0.f, 0.f, 0.f};
      acc[mt][nt] = z;
    }
  __syncthreads();

  const unsigned short* w2l = w2b + (size_t)lane * 8;
#pragma unroll
  for (int tap = 0; tap < 9; ++tap) {
    const int ky = tap / 3, kx = tap % 3;
#pragma unroll
    for (int cc = 0; cc < 2; ++cc) {
      short8 bf[4];
#pragma unroll
      for (int nt = 0; nt < 4; ++nt)
        bf[nt] = *(const short8*)(
            w2l + (size_t)((tap * 8 + wn * 4 + nt) * 2 + cc) * 512);
      short8 af[2];
#pragma unroll
      for (int mt = 0; mt < 2; ++mt) {
        const int c = 2 * (wm * 32 + mt * 16 + lr) + kx;
        const int hh = (cc * 4 + lg) ^ ((c >> 1) & 7);
        af[mt] = *(const short8*)(Asw2 + (size_t)(ky * 1032 + c * 8 + hh) * 8);
      }
#pragma unroll
      for (int nt = 0; nt < 4; ++nt)
#pragma unroll
        for (int mt = 0; mt < 2; ++mt)
          acc[mt][nt] = __builtin_amdgcn_mfma_f32_16x16x32_bf16(
              af[mt], bf[nt], acc[mt][nt], 0, 0, 0);
    }
  }

  float b2v[4];
#pragma unroll
  for (int nt = 0; nt < 4; ++nt) b2v[nt] = b2[wn * 64 + nt * 16 + lr];
#pragma unroll
  for (int mt = 0; mt < 2; ++mt) {
#pragma unroll
    for (int nt = 0; nt < 4; ++nt) {
      const int px = wm * 32 + mt * 16 + lg * 4;
      const int co = wn * 64 + nt * 16 + lr;
      float4 v;
      v.x = acc[mt][nt][0] + b2v[nt];
      v.y = acc[mt][nt][1] + b2v[nt];
      v.z = acc[mt][nt][2] + b2v[nt];
      v.w = acc[mt][nt][3] + b2v[nt];
      *(float4*)(x2 + ((size_t)(b * 128 + co)) * 4096 + oy * 64 + px) = v;
    }
  }
}

// -------- transpose x2: fp32 [b][128][4096] -> X2p bf16 [b][65][65][128] ----
__global__ __launch_bounds__(256) void transpose_x2_kernel(
    const float* __restrict__ x2, unsigned short* __restrict__ X2p) {
  const int b = blockIdx.y;
  const int p0 = (blockIdx.x & 63) * 64;
  const int ci0 = (blockIdx.x >> 6) * 64;
  __shared__ unsigned short T[64][66];
  const float* src = x2 + (size_t)b * 128 * 4096;
  const int t = threadIdx.x;
#pragma unroll
  for (int r = 0; r < 16; ++r) {
    const int ci_l = r * 4 + (t >> 6);
    const int p_l = t & 63;
    T[ci_l][p_l] = f2bf(src[(size_t)(ci0 + ci_l) * 4096 + p0 + p_l]);
  }
  __syncthreads();
  unsigned short* dst = X2p + (size_t)b * 65 * 65 * 128;
#pragma unroll
  for (int r = 0; r < 2; ++r) {
    const int p_l = r * 32 + (t >> 3);
    const int c0 = (t & 7) * 8;
    union { short8 v; unsigned short u[8]; } pk;
#pragma unroll
    for (int j = 0; j < 8; ++j) pk.u[j] = T[c0 + j][p_l];
    const int p = p0 + p_l;
    const int yy = p >> 6, xx = p & 63;
    *(short8*)(dst + ((size_t)yy * 65 + xx) * 128 + ci0 + c0) = pk.v;
  }
}

// ---------------- zero pad row 64 / col 64 of X2p ----------------
__global__ __launch_bounds__(256) void zpad_x2_kernel(unsigned short* __restrict__ X2p) {
  const int b = blockIdx.x;
  unsigned short* Xb = X2p + (size_t)b * 65 * 65 * 128;
  for (int i = threadIdx.x; i < 129 * 128; i += 256) {
    const int j = i >> 7, ci = i & 127;
    size_t off;
    if (j < 65) off = ((size_t)64 * 65 + j) * 128 + ci;
    else off = ((size_t)(j - 65) * 65 + 64) * 128 + ci;
    Xb[off] = 0;
  }
}

// -------- weight repack (coalesced tiles): wt fp32 [256][128][3][3] ->
// -------- Wtb2 bf16 [9][cot16][c4(4)][lane64][8] ----------------------------
__global__ __launch_bounds__(256) void wtprep_kernel(const float* __restrict__ wt,
                                                     unsigned short* __restrict__ Wtb2) {
  const int i = blockIdx.x * 256 + threadIdx.x;
  if (i >= 9 * 256 * 128) return;
  const int e = i & 7, lane = (i >> 3) & 63, c4 = (i >> 9) & 3;
  const int cot = (i >> 11) & 15, tap = i >> 15;
  const int co = cot * 16 + (lane & 15);
  const int ci = c4 * 32 + (lane >> 4) * 8 + e;
  Wtb2[i] = f2bf(wt[((size_t)co * 128 + ci) * 9 + tap]);
}

// ---------------- convT as bf16 MFMA per-parity-class GEMM ----------------
__global__ __launch_bounds__(256, 3) void convt_mfma_kernel(
    const unsigned short* __restrict__ X2p, const unsigned short* __restrict__ Wtb2,
    const float* __restrict__ bt, unsigned short* __restrict__ Y) {
  const int raw = blockIdx.x;
  const int swz = (raw & 7) * 256 + (raw >> 3);
  const int b = swz >> 8;
  const int rem = swz & 255;
  const int cls = rem >> 6;
  const int sy = rem & 63;
  const int py = cls & 1, px = cls >> 1;

  const int kyA = py ? 0 : 1, kxA = px ? 0 : 1;
  int tk[4], tdy[4], tdx[4];
  int ntaps = 0;
  tk[ntaps] = kyA * 3 + kxA; tdy[ntaps] = 0; tdx[ntaps] = 0; ++ntaps;
  if (px) { tk[ntaps] = kyA * 3 + 2; tdy[ntaps] = 0; tdx[ntaps] = 1; ++ntaps; }
  if (py) { tk[ntaps] = 6 + kxA; tdy[ntaps] = 1; tdx[ntaps] = 0; ++ntaps; }
  if (py && px) { tk[ntaps] = 8; tdy[ntaps] = 1; tdx[ntaps] = 1; ++ntaps; }

  constexpr int CS = 36;
  constexpr int BUFN = 2 * 65 * CS;
  __shared__ unsigned short As2[2 * BUFN];

  const int t = threadIdx.x;
  const int lane = t & 63;
  const int wn = t >> 6;
  const int lg = lane >> 4, lr = lane & 15;
  const int co_w = wn * 64;

  const unsigned short* Xb = X2p + (size_t)b * 65 * 65 * 128;

  int dof0, dof1, dof2;
  const unsigned short *sp0, *sp1, *sp2;
  bool sv2;
  {
    const int i0 = t, i1 = t + 256, i2 = t + 512;
    const int r0 = i0 / 260, c0_ = (i0 % 260) >> 2, h0 = i0 & 3;
    const int r1 = i1 / 260, c1_ = (i1 % 260) >> 2, h1 = i1 & 3;
    sv2 = i2 < 520;
    const int i2c = sv2 ? i2 : 512;
    const int r2 = i2c / 260, c2_ = (i2c % 260) >> 2, h2 = i2c & 3;
    dof0 = (r0 * 65 + c0_) * CS + h0 * 8;
    dof1 = (r1 * 65 + c1_) * CS + h1 * 8;
    dof2 = (r2 * 65 + c2_) * CS + h2 * 8;
    sp0 = Xb + ((size_t)(sy + r0) * 65 + c0_) * 128 + h0 * 8;
    sp1 = Xb + ((size_t)(sy + r1) * 65 + c1_) * 128 + h1 * 8;
    sp2 = Xb + ((size_t)(sy + r2) * 65 + c2_) * 128 + h2 * 8;
  }

  f32x4 acc[4][4];
#pragma unroll
  for (int mt = 0; mt < 4; ++mt)
#pragma unroll
    for (int nt = 0; nt < 4; ++nt) {
      f32x4 z = {0.f, 0.f, 0.f, 0.f};
      acc[mt][nt] = z;
    }

  {
    const short8 a = *(const short8*)sp0;
    const short8 bq = *(const short8*)sp1;
    short8 cq;
    if (sv2) cq = *(const short8*)sp2;
    *(short8*)(As2 + dof0) = a;
    *(short8*)(As2 + dof1) = bq;
    if (sv2) *(short8*)(As2 + dof2) = cq;
  }
  __syncthreads();

  const unsigned short* wlane = Wtb2 + (size_t)lane * 8;

  for (int c8 = 0; c8 < 4; ++c8) {
    short8 n0, n1, n2;
    if (c8 < 3) {
      const int cn = (c8 + 1) * 32;
      n0 = *(const short8*)(sp0 + cn);
      n1 = *(const short8*)(sp1 + cn);
      if (sv2) n2 = *(const short8*)(sp2 + cn);
    }
    const unsigned short* Ab = As2 + (c8 & 1) * BUFN;
    for (int tp = 0; tp < ntaps; ++tp) {
      const int dy = tdy[tp], dx = tdx[tp];
      short8 af[4];
#pragma unroll
      for (int mt = 0; mt < 4; ++mt)
        af[mt] = *(const short8*)(Ab + (dy * 65 + mt * 16 + lr + dx) * CS + lg * 8);
      const unsigned short* wt_ =
          wlane + (size_t)(((tk[tp] * 16 + wn * 4) * 4) + c8) * 512;
#pragma unroll
      for (int nt = 0; nt < 4; ++nt) {
        const short8 bf = *(const short8*)(wt_ + (size_t)nt * (4 * 512));
#pragma unroll
        for (int mt = 0; mt < 4; ++mt)
          acc[mt][nt] = __builtin_amdgcn_mfma_f32_16x16x32_bf16(
              af[mt], bf, acc[mt][nt], 0, 0, 0);
      }
    }
    if (c8 < 3) {
      unsigned short* Db = As2 + ((c8 + 1) & 1) * BUFN;
      *(short8*)(Db + dof0) = n0;
      *(short8*)(Db + dof1) = n1;
      if (sv2) *(short8*)(Db + dof2) = n2;
    }
    __syncthreads();
  }

  const int oy = 2 * sy + py;
  unsigned short* Yb = Y + ((size_t)b * 16384 + (size_t)oy * 128 + px) * 256;
  float bco[4];
#pragma unroll
  for (int nt = 0; nt < 4; ++nt) bco[nt] = bt[co_w + nt * 16 + lr];
#pragma unroll
  for (int mt = 0; mt < 4; ++mt) {
#pragma unroll
    for (int r = 0; r < 4; ++r) {
      const int sx = mt * 16 + lg * 4 + r;
      unsigned short* yp = Yb + (size_t)(2 * sx) * 256 + co_w + lr;
#pragma unroll
      for (int nt = 0; nt < 4; ++nt)
        yp[nt * 16] = f2bf(acc[mt][nt][r] + bco[nt]);
    }
  }
}

// ------- instance-norm stats over pixel-major Y (short8, LDS-reduced) -------
__global__ __launch_bounds__(256) void inorm_stats_kernel(
    const unsigned short* __restrict__ Y, float* __restrict__ ssum,
    float* __restrict__ ssq) {
  const int b = blockIdx.y, sl = blockIdx.x;
  const int t = threadIdx.x;
  const int rg = t >> 5;
  const int c0 = (t & 31) * 8;
  const unsigned short* base = Y + ((size_t)b * 16384 + sl * 256) * 256;
  float s[8], q[8];
#pragma unroll
  for (int j = 0; j < 8; ++j) { s[j] = 0.f; q[j] = 0.f; }
  for (int i = 0; i < 32; ++i) {
    union { short8 v; unsigned short u[8]; } pk;
    pk.v = *(const short8*)(base + (size_t)(rg + i * 8) * 256 + c0);
#pragma unroll
    for (int j = 0; j < 8; ++j) {
      const float v = bf2f(pk.u[j]);
      s[j] += v;
      q[j] += v * v;
    }
  }
  __shared__ float sm[2][8][256];
#pragma unroll
  for (int j = 0; j < 8; ++j) {
    sm[0][rg][c0 + j] = s[j];
    sm[1][rg][c0 + j] = q[j];
  }
  __syncthreads();
  float ts = 0.f, tq = 0.f;
#pragma unroll
  for (int g = 0; g < 8; ++g) {
    ts += sm[0][g][t];
    tq += sm[1][g][t];
  }
  atomicAdd(&ssum[b * 256 + t], ts);
  atomicAdd(&ssq[b * 256 + t], tq);
}

// ------- apply IN + LReLU to Y (short8), write bf16 into Xpad interior -------
__global__ __launch_bounds__(256) void inorm_apply_kernel(
    const unsigned short* __restrict__ Y, const float* __restrict__ ssum,
    const float* __restrict__ ssq, unsigned short* __restrict__ Xpad) {
  const int b = blockIdx.y, sl = blockIdx.x;
  const int t = threadIdx.x;
  const int rg = t >> 5;
  const int c0 = (t & 31) * 8;
  float m[8], r[8];
#pragma unroll
  for (int j = 0; j < 8; ++j) {
    const float mm = ssum[b * 256 + c0 + j] * (1.f / 16384.f);
    float var = ssq[b * 256 + c0 + j] * (1.f / 16384.f) - mm * mm;
    var = var < 0.f ? 0.f : var;
    m[j] = mm;
    r[j] = rsqrtf(var + 1e-5f);
  }
  const unsigned short* base = Y + ((size_t)b * 16384 + sl * 256) * 256;
  unsigned short* dstb = Xpad + (size_t)b * 130 * 130 * 256;
  for (int i = 0; i < 32; ++i) {
    const int row = sl * 256 + rg + i * 8;
    const int yy = row >> 7, xx = row & 127;
    union { short8 v; unsigned short u[8]; } pk;
    pk.v = *(const short8*)(base + (size_t)(rg + i * 8) * 256 + c0);
#pragma unroll
    for (int j = 0; j < 8; ++j) {
      float v = bf2f(pk.u[j]);
      v = (v - m[j]) * r[j];
      v = v >= 0.f ? v : 0.2f * v;
      pk.u[j] = f2bf(v);
    }
    *(short8*)(dstb + ((size_t)(yy + 1) * 130 + (xx + 1)) * 256 + c0) = pk.v;
  }
}

// ---------------- reflect borders of Xpad: rows then cols ----------------
__global__ __launch_bounds__(256) void pad_rows_kernel(unsigned short* __restrict__ Xp) {
  const int b = blockIdx.x >> 1, side = blockIdx.x & 1;
  unsigned short* Xb = Xp + (size_t)b * 130 * 130 * 256;
  const int dr = side ? 129 : 0, sr = side ? 127 : 2;
  for (int i = threadIdx.x; i < 4096; i += 256) {
    const int c = 1 + (i >> 5), o = (i & 31) * 8;
    *(short8*)(Xb + ((size_t)dr * 130 + c) * 256 + o) =
        *(const short8*)(Xb + ((size_t)sr * 130 + c) * 256 + o);
  }
}
__global__ __launch_bounds__(256) void pad_cols_kernel(unsigned short* __restrict__ Xp) {
  const int b = blockIdx.x >> 1, side = blockIdx.x & 1;
  unsigned short* Xb = Xp + (size_t)b * 130 * 130 * 256;
  const int dc = side ? 129 : 0, sc = side ? 127 : 2;
  for (int i = threadIdx.x; i < 130 * 32; i += 256) {
    const int r = i >> 5, o = (i & 31) * 8;
    *(short8*)(Xb + ((size_t)r * 130 + dc) * 256 + o) =
        *(const short8*)(Xb + ((size_t)r * 130 + sc) * 256 + o);
  }
}

// ------ weight repack (coalesced tiles): w3 fp32 [512][256][9] ->
// ------ Wb2 bf16 [9][cot32][c8(8)][lane64][8]; co=cot*16+lr, ci=c8*32+lg*8+e
__global__ __launch_bounds__(256) void wprep_kernel(const float* __restrict__ w3,
                                                    unsigned short* __restrict__ Wb2) {
  const int i = blockIdx.x * 256 + threadIdx.x;
  if (i >= 9 * 512 * 256) return;
  const int e = i & 7, lane = (i >> 3) & 63, c8 = (i >> 9) & 7;
  const int cot = (i >> 12) & 31, tap = i >> 17;
  const int co = cot * 16 + (lane & 15);
  const int ci = c8 * 32 + (lane >> 4) * 8 + e;
  Wb2[i] = f2bf(w3[((size_t)co * 256 + ci) * 9 + tap]);
}

// ---------------- label extraction + counts from one-hot segmap ----------------
__global__ __launch_bounds__(256) void label_kernel(
    const float* __restrict__ segmap, int* __restrict__ labels,
    float* __restrict__ cnt) {
  const int b = blockIdx.y;
  const int p = blockIdx.x * 256 + threadIdx.x;
  const int i = p >> 7, j = p & 127;
  const float* sp = segmap + (size_t)b * 19 * 65536 + (2 * i) * 256 + 2 * j;
  int lab = 0;
#pragma unroll
  for (int s = 0; s < 19; ++s)
    if (sp[(size_t)s * 65536] != 0.f) lab = s;
  labels[b * 16384 + p] = lab;
  atomicAdd(&cnt[b * 19 + lab], 1.0f);
}

// ---------------- conv3: bf16 MFMA implicit GEMM + tanh + region pool --------
// R11 structure (reverted from R12): block = 4 waves = 128px x 128co,
// wave tile 64x64, 3 blocks/CU; A-halo async gload_lds + XOR pair; bfv[4]
// loaded per tap inline (no ping-pong arrays — they spill, proven twice).
__global__ __launch_bounds__(256, 3) void conv3_mfma_pool_kernel(
    const unsigned short* __restrict__ Xpad, const unsigned short* __restrict__ Wb2,
    const float* __restrict__ bias, const int* __restrict__ labels,
    float* __restrict__ sums) {
  const int raw = blockIdx.x;
  const int swz = (raw & 7) * 512 + (raw >> 3);
  const int b = swz >> 9;
  const int rem = swz & 511;
  const int y = rem >> 2;
  const int coq = rem & 3;

  constexpr int SLOTS = 1600;
  __shared__ unsigned short Asw[2 * SLOTS * 8];
  float* lsum = (float*)Asw;

  const int t = threadIdx.x;
  const int lane = t & 63;
  const int wave = t >> 6;
  const int wm = wave >> 1;
  const int wn = wave & 1;
  const int lg = lane >> 4, lr = lane & 15;
  const int co_w = coq * 128 + wn * 64;

  const unsigned short* Xb = Xpad + (size_t)b * 130 * 130 * 256;

  const unsigned short* sp[7];
  {
#pragma unroll
    for (int k = 0; k < 7; ++k) {
      int s;
      if (k < 6) s = t + k * 256;
      else s = (t < 24) ? (1536 + t) : 1536;
      const int r = s / 520, rm = s % 520, c = rm >> 2, hs = rm & 3;
      const int E = r * 130 + c;
      const int h = hs ^ ((E >> 1) & 3);
      sp[k] = Xb + ((size_t)(y + r) * 130 + c) * 256 + h * 8;
    }
  }

  f32x4 acc[4][4];
#pragma unroll
  for (int mt = 0; mt < 4; ++mt)
#pragma unroll
    for (int nt = 0; nt < 4; ++nt) {
      f32x4 z = {0.f, 0.f, 0.f, 0.f};
      acc[mt][nt] = z;
    }

  const unsigned short* wlane = Wb2 + (size_t)lane * 8;

  const int wslot = wave * 64;
#define STAGE(bufSel, off)                                                   \
  {                                                                          \
    unsigned short* base_ = Asw + (bufSel) * (SLOTS * 8);                    \
    gload_lds16(sp[0] + (off), base_ + (size_t)wslot * 8);                   \
    gload_lds16(sp[1] + (off), base_ + (size_t)(wslot + 256) * 8);           \
    gload_lds16(sp[2] + (off), base_ + (size_t)(wslot + 512) * 8);           \
    gload_lds16(sp[3] + (off), base_ + (size_t)(wslot + 768) * 8);           \
    gload_lds16(sp[4] + (off), base_ + (size_t)(wslot + 1024) * 8);          \
    gload_lds16(sp[5] + (off), base_ + (size_t)(wslot + 1280) * 8);          \
    if (wave == 0 && lane < 24)                                              \
      gload_lds16(sp[6] + (off), base_ + (size_t)1536 * 8);                  \
  }

  STAGE(0, 0)
  __syncthreads();

  for (int c8 = 0; c8 < 8; ++c8) {
    if (c8 < 7) STAGE((c8 + 1) & 1, (c8 + 1) * 32)
    const unsigned short* Ab = Asw + (c8 & 1) * (SLOTS * 8);
#pragma unroll
    for (int ky = 0; ky < 3; ++ky) {
#pragma unroll
      for (int kx = 0; kx < 3; ++kx) {
        const unsigned short* wt_ =
            wlane +
            (size_t)(((ky * 3 + kx) * 32 + coq * 8 + wn * 4) * 8 + c8) * 512;
        short8 bfv[4];
#pragma unroll
        for (int nt = 0; nt < 4; ++nt)
          bfv[nt] = *(const short8*)(wt_ + (size_t)nt * (8 * 512));
        short8 af[4];
#pragma unroll
        for (int mt = 0; mt < 4; ++mt) {
          const int E = ky * 130 + wm * 64 + mt * 16 + lr + kx;
          const int hh = lg ^ ((E >> 1) & 3);
          af[mt] = *(const short8*)(Ab + (size_t)E * 32 + hh * 8);
        }
#pragma unroll
        for (int nt = 0; nt < 4; ++nt) {
#pragma unroll
          for (int mt = 0; mt < 4; ++mt)
            acc[mt][nt] = __builtin_amdgcn_mfma_f32_16x16x32_bf16(
                af[mt], bfv[nt], acc[mt][nt], 0, 0, 0);
        }
      }
    }
    __syncthreads();
  }
#undef STAGE

  for (int i = t; i < 19 * 128; i += 256) lsum[i] = 0.f;
  __syncthreads();

  const int* labp = labels + b * 16384 + y * 128;
  float bco[4];
#pragma unroll
  for (int nt = 0; nt < 4; ++nt) bco[nt] = bias[co_w + nt * 16 + lr];
#pragma unroll
  for (int mt = 0; mt < 4; ++mt) {
#pragma unroll
    for (int r = 0; r < 4; ++r) {
      const int lab = labp[wm * 64 + mt * 16 + lg * 4 + r];
#pragma unroll
      for (int nt = 0; nt < 4; ++nt) {
        const float v = tanh_fast(acc[mt][nt][r] + bco[nt]);
        atomicAdd(&lsum[lab * 128 + wn * 64 + nt * 16 + lr], v);
      }
    }
  }
  __syncthreads();
  for (int i = t; i < 19 * 128; i += 256) {
    const float v = lsum[i];
    if (v != 0.f) {
      const int sI = i >> 7, c = i & 127;
      atomicAdd(&sums[((size_t)b * 19 + sI) * 512 + coq * 128 + c], v);
    }
  }
}

// ---------------- finalize: out = cnt>0 ? sums/max(cnt,1) : 0 ----------------
__global__ __launch_bounds__(256) void finalize_kernel(
    const float* __restrict__ sums, const float* __restrict__ cnt,
    float* __restrict__ out) {
  const int i = blockIdx.x * 256 + threadIdx.x;
  if (i >= B * 19 * 512) return;
  const int bs = i >> 9;
  const float c = cnt[bs];
  out[i] = c > 0.f ? sums[i] / fmaxf(c, 1.f) : 0.f;
}

// ---------------------------------------------------------------------------
extern "C" void kernel_launch(void* const* d_in, const int* in_sizes, int n_in,
                              void* d_out, int out_size, void* d_ws,
                              size_t ws_size, hipStream_t stream) {
  const float* input = (const float*)d_in[0];
  const float* segmap = (const float*)d_in[1];
  const float* w0 = (const float*)d_in[2];
  const float* b0 = (const float*)d_in[3];
  const float* w1 = (const float*)d_in[4];
  const float* b1 = (const float*)d_in[5];
  const float* w2 = (const float*)d_in[6];
  const float* b2 = (const float*)d_in[7];
  const float* wt = (const float*)d_in[8];
  const float* bt = (const float*)d_in[9];
  const float* w3 = (const float*)d_in[10];
  const float* b3 = (const float*)d_in[11];
  float* out = (float*)d_out;

  float* ws = (float*)d_ws;
  float* x0 = ws;                                    // 16,777,216 f
  float* x1 = x0 + 16777216;                         //  8,388,608 f
  float* x2 = x1 + 8388608;                          //  4,194,304 f
  unsigned short* X2p = (unsigned short*)(x2 + 4194304);  // 4,326,400 us
  unsigned short* Y = X2p + 4326400;                 // 33,554,432 us
  float* sums = (float*)(Y + 33554432);              //     77,824 f
  float* cnt = sums + 77824;                         //        152 f
  float* ssum = cnt + 152;                           //      2,048 f
  float* ssq = ssum + 2048;                          //      2,048 f
  int* labels = (int*)(ssq + 2048);                  //    131,072 i
  unsigned short* Wb2 = (unsigned short*)(labels + 131072);  // 1,179,648 us
  unsigned short* Wtb2 = Wb2 + 1179648;              //    294,912 us
  unsigned short* w1b = Wtb2 + 294912;               //     18,432 us
  unsigned short* w2b = w1b + 18432;                 //     73,728 us
  unsigned short* Xpad = (unsigned short*)ws;        // 69.2MB over x0+x1 (dead)
  // Xp0/Xp1 overlay Y (Y written only from convt onward; both dead by then)
  unsigned short* Xp0 = Y;                           // 17,040,384 us
  unsigned short* Xp1 = Y + 17040384;                //  8,652,800 us

  hipMemsetAsync(sums, 0, (77824 + 152 + 2048 + 2048) * sizeof(float), stream);

  wprep_kernel<<<dim3((9 * 512 * 256 + 255) / 256), 256, 0, stream>>>(w3, Wb2);
  wtprep_kernel<<<dim3((9 * 256 * 128 + 255) / 256), 256, 0, stream>>>(wt, Wtb2);
  w1prep_kernel<<<dim3((9 * 64 * 32 + 255) / 256), 256, 0, stream>>>(w1, w1b);
  w2prep_kernel<<<dim3((9 * 128 * 64 + 255) / 256), 256, 0, stream>>>(w2, w2b);

  conv0_kernel<<<dim3(256, B), 256, 0, stream>>>(input, w0, b0, x0);
  inorm_lrelu_kernel<<<dim3(B * 32), 256, 0, stream>>>(x0, 65536);
  transpose_x0_kernel<<<dim3(1024, B), 256, 0, stream>>>(x0, Xp0);
  zpad0_kernel<<<dim3(B), 256, 0, stream>>>(Xp0);
  conv1_mfma_kernel<<<dim3(1024), 256, 0, stream>>>(Xp0, w1b, b1, x1);
  inorm_lrelu_kernel<<<dim3(B * 64), 256, 0, stream>>>(x1, 16384);
  transpose_x1_kernel<<<dim3(256, B), 256, 0, stream>>>(x1, Xp1);
  zpad1_kernel<<<dim3(B), 256, 0, stream>>>(Xp1);
  conv2_mfma_kernel<<<dim3(512), 256, 0, stream>>>(Xp1, w2b, b2, x2);
  inorm_lrelu_kernel<<<dim3(B * 128), 256, 0, stream>>>(x2, 4096);
  transpose_x2_kernel<<<dim3(128, B), 256, 0, stream>>>(x2, X2p);
  zpad_x2_kernel<<<dim3(B), 256, 0, stream>>>(X2p);
  convt_mfma_kernel<<<dim3(2048), 256, 0, stream>>>(X2p, Wtb2, bt, Y);
  inorm_stats_kernel<<<dim3(64, B), 256, 0, stream>>>(Y, ssum, ssq);
  inorm_apply_kernel<<<dim3(64, B), 256, 0, stream>>>(Y, ssum, ssq, Xpad);
  pad_rows_kernel<<<dim3(2 * B), 256, 0, stream>>>(Xpad);
  pad_cols_kernel<<<dim3(2 * B), 256, 0, stream>>>(Xpad);
  label_kernel<<<dim3(64, B), 256, 0, stream>>>(segmap, labels, cnt);
  conv3_mfma_pool_kernel<<<dim3(4096), 256, 0, stream>>>(Xpad, Wb2, b3, labels, sums);
  finalize_kernel<<<dim3((B * 19 * 512 + 255) / 256), 256, 0, stream>>>(sums, cnt, out);
}

// Round 15
// 908.570 us; speedup vs baseline: 1.6002x; 1.0586x over previous
//
#include <hip/hip_runtime.h>

// ---------------------------------------------------------------------------
// SPADE-style encoder — all four big convs bf16 MFMA implicit-GEMM.
// R15: tail overhaul. conv0/1/2 write bf16 pixel-major DIRECTLY (raw+bias);
//      templated stats/apply kernels do IN+LReLU in place (deletes 3 inorm
//      + 3 transpose passes and the fp32 x0/x1/x2 buffers). convT rewritten:
//      whole 2x65x128 halo staged once via gload_lds (+XOR pair), ONE
//      barrier, K-loop pure-LDS; Y IN-stats fused into its epilogue.
// conv3: R11/R14 structure, untouched (612us, proven).
// ---------------------------------------------------------------------------

#define B 8

typedef __attribute__((ext_vector_type(8))) short short8;
typedef __attribute__((ext_vector_type(4))) float f32x4;

static __device__ __forceinline__ unsigned short f2bf(float f) {
  union { float f; unsigned u; } v;
  v.f = f;
  unsigned r = v.u + 0x7fffu + ((v.u >> 16) & 1u);
  return (unsigned short)(r >> 16);
}
static __device__ __forceinline__ float bf2f(unsigned short h) {
  union { unsigned u; float f; } v;
  v.u = (unsigned)h << 16;
  return v.f;
}
static __device__ __forceinline__ float tanh_fast(float x) {
  float ax = fabsf(x);
  ax = fminf(ax, 20.f);
  const float e = __expf(-2.f * ax);
  const float t = (1.f - e) / (1.f + e);
  return __builtin_copysignf(t, x);
}

// async 16B global -> LDS (dest is wave-uniform base; HW adds lane*16)
static __device__ __forceinline__ void gload_lds16(const unsigned short* g,
                                                   unsigned short* l) {
  __builtin_amdgcn_global_load_lds(
      (const __attribute__((address_space(1))) unsigned int*)(const void*)g,
      (__attribute__((address_space(3))) unsigned int*)(void*)l, 16, 0, 0);
}

// ------- conv0: 3->32, reflect pad, 256x256; writes Xp0 bf16 px-major -------
__global__ __launch_bounds__(256) void conv0_kernel(
    const float* __restrict__ in, const float* __restrict__ w,
    const float* __restrict__ bias, unsigned short* __restrict__ Xp0) {
  __shared__ float sw[32 * 27 + 32];
  for (int i = threadIdx.x; i < 32 * 27; i += 256) sw[i] = w[i];
  if (threadIdx.x < 32) sw[32 * 27 + threadIdx.x] = bias[threadIdx.x];
  __syncthreads();
  const int b = blockIdx.y;
  const int p = blockIdx.x * 256 + threadIdx.x;
  const int y = p >> 8, x = p & 255;
  const float* inb = in + (size_t)b * 3 * 65536;
  float v[27];
#pragma unroll
  for (int c = 0; c < 3; ++c) {
#pragma unroll
    for (int ky = 0; ky < 3; ++ky) {
      int iy = y + ky - 1;
      iy = iy < 0 ? -iy : (iy > 255 ? 510 - iy : iy);
#pragma unroll
      for (int kx = 0; kx < 3; ++kx) {
        int ix = x + kx - 1;
        ix = ix < 0 ? -ix : (ix > 255 ? 510 - ix : ix);
        v[c * 9 + ky * 3 + kx] = inb[c * 65536 + iy * 256 + ix];
      }
    }
  }
  unsigned short* ob =
      Xp0 + ((size_t)b * 258 * 258 + (size_t)(y + 1) * 258 + (x + 1)) * 32;
#pragma unroll
  for (int q = 0; q < 4; ++q) {
    union { short8 v8; unsigned short u[8]; } pk;
#pragma unroll
    for (int j = 0; j < 8; ++j) {
      const int co = q * 8 + j;
      float a = sw[32 * 27 + co];
#pragma unroll
      for (int k = 0; k < 27; ++k) a = fmaf(v[k], sw[co * 27 + k], a);
      pk.u[j] = f2bf(a);
    }
    *(short8*)(ob + q * 8) = pk.v8;
  }
}

// ------- per-channel IN stats over pixel-major bf16 tensor (templated) ------
template <int C, int WLOG, int STR, int SH, int ITER>
__global__ __launch_bounds__(256) void stats_px_kernel(
    const unsigned short* __restrict__ X, float* __restrict__ ssum,
    float* __restrict__ ssq) {
  constexpr int G = C / 8;
  constexpr int R = 256 / G;
  const int b = blockIdx.y;
  const int t = threadIdx.x;
  const int rg = t / G;
  const int cg = (t % G) * 8;
  const int px0 = blockIdx.x * (R * ITER);
  const unsigned short* Xb = X + (size_t)b * STR * STR * C;
  float s[8], q[8];
#pragma unroll
  for (int j = 0; j < 8; ++j) { s[j] = 0.f; q[j] = 0.f; }
  for (int i = 0; i < ITER; ++i) {
    const int p = px0 + i * R + rg;
    const int yy = p >> WLOG, xx = p & ((1 << WLOG) - 1);
    union { short8 v8; unsigned short u[8]; } pk;
    pk.v8 = *(const short8*)(Xb + ((size_t)(yy + SH) * STR + (xx + SH)) * C + cg);
#pragma unroll
    for (int j = 0; j < 8; ++j) {
      const float v = bf2f(pk.u[j]);
      s[j] += v;
      q[j] += v * v;
    }
  }
  __shared__ float sm[2][R][C];
#pragma unroll
  for (int j = 0; j < 8; ++j) {
    sm[0][rg][cg + j] = s[j];
    sm[1][rg][cg + j] = q[j];
  }
  __syncthreads();
  if (t < C) {
    float ts = 0.f, tq = 0.f;
    for (int g2 = 0; g2 < R; ++g2) {
      ts += sm[0][g2][t];
      tq += sm[1][g2][t];
    }
    atomicAdd(&ssum[b * C + t], ts);
    atomicAdd(&ssq[b * C + t], tq);
  }
}

// ------- apply IN + LReLU in place on pixel-major bf16 tensor ---------------
template <int C, int WLOG, int STR, int SH>
__global__ __launch_bounds__(256) void apply_px_kernel(
    unsigned short* __restrict__ X, const float* __restrict__ ssum,
    const float* __restrict__ ssq) {
  constexpr int G = C / 8;
  const int b = blockIdx.y;
  const int i = blockIdx.x * 256 + threadIdx.x;
  const int p = i / G;
  const int cg = (i % G) * 8;
  const int yy = p >> WLOG, xx = p & ((1 << WLOG) - 1);
  constexpr float inv = 1.f / (float)(1 << (2 * WLOG));
  float m[8], r[8];
#pragma unroll
  for (int j = 0; j < 8; ++j) {
    const float mm = ssum[b * C + cg + j] * inv;
    float var = ssq[b * C + cg + j] * inv - mm * mm;
    var = var < 0.f ? 0.f : var;
    m[j] = mm;
    r[j] = rsqrtf(var + 1e-5f);
  }
  unsigned short* pp =
      X + (size_t)b * STR * STR * C + ((size_t)(yy + SH) * STR + (xx + SH)) * C + cg;
  union { short8 v8; unsigned short u[8]; } pk;
  pk.v8 = *(const short8*)pp;
#pragma unroll
  for (int j = 0; j < 8; ++j) {
    float v = bf2f(pk.u[j]);
    v = (v - m[j]) * r[j];
    v = v >= 0.f ? v : 0.2f * v;
    pk.u[j] = f2bf(v);
  }
  *(short8*)pp = pk.v8;
}

// ---------------- zero row 0 / col 0 of Xp0 ----------------
__global__ __launch_bounds__(256) void zpad0_kernel(unsigned short* __restrict__ Xp0) {
  const int b = blockIdx.x;
  unsigned short* Xb = Xp0 + (size_t)b * 258 * 258 * 32;
  const short8 z = {0, 0, 0, 0, 0, 0, 0, 0};
  for (int i = threadIdx.x; i < 258 * 4; i += 256) {
    const int c = i >> 2, q = (i & 3) * 8;
    *(short8*)(Xb + ((size_t)0 * 258 + c) * 32 + q) = z;
    *(short8*)(Xb + ((size_t)c * 258 + 0) * 32 + q) = z;
  }
}

// ---- w1 repack: [64][32][3][3] fp32 -> w1b bf16 [9][cot4][lane64][8] ----
__global__ __launch_bounds__(256) void w1prep_kernel(const float* __restrict__ w1,
                                                     unsigned short* __restrict__ w1b) {
  const int i = blockIdx.x * 256 + threadIdx.x;
  if (i >= 9 * 64 * 32) return;
  const int e = i & 7, lane = (i >> 3) & 63, cot = (i >> 9) & 3, tap = i >> 11;
  const int co = cot * 16 + (lane & 15);
  const int ci = (lane >> 4) * 8 + e;
  w1b[i] = f2bf(w1[((size_t)co * 32 + ci) * 9 + tap]);
}

// ------- conv1: 32->64 stride-2 MFMA; writes Xp1 bf16 px-major (raw+bias) ----
__global__ __launch_bounds__(256, 3) void conv1_mfma_kernel(
    const unsigned short* __restrict__ Xp0, const unsigned short* __restrict__ w1b,
    const float* __restrict__ b1, unsigned short* __restrict__ Xp1) {
  const int raw = blockIdx.x;  // 1024 = 8 XCD x 128
  const int swz = (raw & 7) * 128 + (raw >> 3);
  const int b = swz >> 7;
  const int oy = swz & 127;

  __shared__ unsigned short Asw1[3084 * 8];  // 48.2 KB

  const int t = threadIdx.x;
  const int lane = t & 63;
  const int wave = t >> 6;
  const int wm = wave >> 1, wn = wave & 1;
  const int lg = lane >> 4, lr = lane & 15;
  const int wslot = wave * 64;

  const unsigned short* Xb = Xp0 + (size_t)b * 258 * 258 * 32;

#pragma unroll
  for (int k = 0; k < 13; ++k) {
    int s;
    bool act = true;
    if (k < 12) s = t + k * 256;
    else { s = 3072 + lane; act = (wave == 0 && lane < 12); }
    const int r = s / 1028, rm = s % 1028, c = rm >> 2, hs = rm & 3;
    const int h = hs ^ ((c >> 1) & 3);
    const unsigned short* gsrc = Xb + ((size_t)(2 * oy + r) * 258 + c) * 32 + h * 8;
    unsigned short* ldst = (k < 12) ? (Asw1 + (size_t)(k * 256 + wslot) * 8)
                                    : (Asw1 + (size_t)3072 * 8);
    if (act) gload_lds16(gsrc, ldst);
  }

  f32x4 acc[4][2];
#pragma unroll
  for (int mt = 0; mt < 4; ++mt)
#pragma unroll
    for (int nt = 0; nt < 2; ++nt) {
      f32x4 z = {0.f, 0.f, 0.f, 0.f};
      acc[mt][nt] = z;
    }
  __syncthreads();

  const unsigned short* w1l = w1b + (size_t)lane * 8;
#pragma unroll
  for (int tap = 0; tap < 9; ++tap) {
    const int ky = tap / 3, kx = tap % 3;
    short8 bf[2];
#pragma unroll
    for (int nt = 0; nt < 2; ++nt)
      bf[nt] = *(const short8*)(w1l + (size_t)(tap * 4 + wn * 2 + nt) * 512);
    short8 af[4];
#pragma unroll
    for (int mt = 0; mt < 4; ++mt) {
      const int c = 2 * (wm * 64 + mt * 16 + lr) + kx;
      const int hh = lg ^ ((c >> 1) & 3);
      af[mt] = *(const short8*)(Asw1 + (size_t)(ky * 1028 + c * 4 + hh) * 8);
    }
#pragma unroll
    for (int nt = 0; nt < 2; ++nt)
#pragma unroll
      for (int mt = 0; mt < 4; ++mt)
        acc[mt][nt] = __builtin_amdgcn_mfma_f32_16x16x32_bf16(
            af[mt], bf[nt], acc[mt][nt], 0, 0, 0);
  }

  float b1v[2];
#pragma unroll
  for (int nt = 0; nt < 2; ++nt) b1v[nt] = b1[wn * 32 + nt * 16 + lr];
  unsigned short* yb =
      Xp1 + ((size_t)b * 130 * 130 + (size_t)(oy + 1) * 130) * 64;
#pragma unroll
  for (int mt = 0; mt < 4; ++mt) {
#pragma unroll
    for (int r = 0; r < 4; ++r) {
      const int px_ = wm * 64 + mt * 16 + lg * 4 + r;
#pragma unroll
      for (int nt = 0; nt < 2; ++nt) {
        const int co = wn * 32 + nt * 16 + lr;
        yb[(size_t)(px_ + 1) * 64 + co] = f2bf(acc[mt][nt][r] + b1v[nt]);
      }
    }
  }
}

// ---------------- zero row 0 / col 0 of Xp1 ----------------
__global__ __launch_bounds__(256) void zpad1_kernel(unsigned short* __restrict__ Xp1) {
  const int b = blockIdx.x;
  unsigned short* Xb = Xp1 + (size_t)b * 130 * 130 * 64;
  const short8 z = {0, 0, 0, 0, 0, 0, 0, 0};
  for (int i = threadIdx.x; i < 130 * 8; i += 256) {
    const int c = i >> 3, q = (i & 7) * 8;
    *(short8*)(Xb + ((size_t)0 * 130 + c) * 64 + q) = z;
    *(short8*)(Xb + ((size_t)c * 130 + 0) * 64 + q) = z;
  }
}

// ---- w2 repack: [128][64][3][3] fp32 -> w2b bf16 [9][cot8][cc2][lane64][8] --
__global__ __launch_bounds__(256) void w2prep_kernel(const float* __restrict__ w2,
                                                     unsigned short* __restrict__ w2b) {
  const int i = blockIdx.x * 256 + threadIdx.x;
  if (i >= 9 * 128 * 64) return;
  const int e = i & 7, lane = (i >> 3) & 63, cc = (i >> 9) & 1;
  const int cot = (i >> 10) & 7, tap = i >> 13;
  const int co = cot * 16 + (lane & 15);
  const int ci = cc * 32 + (lane >> 4) * 8 + e;
  w2b[i] = f2bf(w2[((size_t)co * 64 + ci) * 9 + tap]);
}

// ------- conv2: 64->128 stride-2 MFMA; writes X2p bf16 px-major (raw+bias) ---
__global__ __launch_bounds__(256, 3) void conv2_mfma_kernel(
    const unsigned short* __restrict__ Xp1, const unsigned short* __restrict__ w2b,
    const float* __restrict__ b2, unsigned short* __restrict__ X2p) {
  const int raw = blockIdx.x;  // 512 = 8 XCD x 64
  const int swz = (raw & 7) * 64 + (raw >> 3);
  const int b = swz >> 6;
  const int oy = swz & 63;

  __shared__ unsigned short Asw2[3096 * 8];  // 48.4 KB

  const int t = threadIdx.x;
  const int lane = t & 63;
  const int wave = t >> 6;
  const int wm = wave >> 1, wn = wave & 1;
  const int lg = lane >> 4, lr = lane & 15;
  const int wslot = wave * 64;

  const unsigned short* Xb = Xp1 + (size_t)b * 130 * 130 * 64;

#pragma unroll
  for (int k = 0; k < 13; ++k) {
    int s;
    bool act = true;
    if (k < 12) s = t + k * 256;
    else { s = 3072 + lane; act = (wave == 0 && lane < 24); }
    const int r = s / 1032, rm = s % 1032, c = rm >> 3, hs = rm & 7;
    const int h = hs ^ ((c >> 1) & 7);
    const unsigned short* gsrc = Xb + ((size_t)(2 * oy + r) * 130 + c) * 64 + h * 8;
    unsigned short* ldst = (k < 12) ? (Asw2 + (size_t)(k * 256 + wslot) * 8)
                                    : (Asw2 + (size_t)3072 * 8);
    if (act) gload_lds16(gsrc, ldst);
  }

  f32x4 acc[2][4];
#pragma unroll
  for (int mt = 0; mt < 2; ++mt)
#pragma unroll
    for (int nt = 0; nt < 4; ++nt) {
      f32x4 z = {0.f, 0.f, 0.f, 0.f};
      acc[mt][nt] = z;
    }
  __syncthreads();

  const unsigned short* w2l = w2b + (size_t)lane * 8;
#pragma unroll
  for (int tap = 0; tap < 9; ++tap) {
    const int ky = tap / 3, kx = tap % 3;
#pragma unroll
    for (int cc = 0; cc < 2; ++cc) {
      short8 bf[4];
#pragma unroll
      for (int nt = 0; nt < 4; ++nt)
        bf[nt] = *(const short8*)(
            w2l + (size_t)((tap * 8 + wn * 4 + nt) * 2 + cc) * 512);
      short8 af[2];
#pragma unroll
      for (int mt = 0; mt < 2; ++mt) {
        const int c = 2 * (wm * 32 + mt * 16 + lr) + kx;
        const int hh = (cc * 4 + lg) ^ ((c >> 1) & 7);
        af[mt] = *(const short8*)(Asw2 + (size_t)(ky * 1032 + c * 8 + hh) * 8);
      }
#pragma unroll
      for (int nt = 0; nt < 4; ++nt)
#pragma unroll
        for (int mt = 0; mt < 2; ++mt)
          acc[mt][nt] = __builtin_amdgcn_mfma_f32_16x16x32_bf16(
              af[mt], bf[nt], acc[mt][nt], 0, 0, 0);
    }
  }

  float b2v[4];
#pragma unroll
  for (int nt = 0; nt < 4; ++nt) b2v[nt] = b2[wn * 64 + nt * 16 + lr];
  unsigned short* yb = X2p + ((size_t)b * 65 * 65 + (size_t)oy * 65) * 128;
#pragma unroll
  for (int mt = 0; mt < 2; ++mt) {
#pragma unroll
    for (int r = 0; r < 4; ++r) {
      const int px_ = wm * 32 + mt * 16 + lg * 4 + r;
#pragma unroll
      for (int nt = 0; nt < 4; ++nt) {
        const int co = wn * 64 + nt * 16 + lr;
        yb[(size_t)px_ * 128 + co] = f2bf(acc[mt][nt][r] + b2v[nt]);
      }
    }
  }
}

// ---------------- zero pad row 64 / col 64 of X2p ----------------
__global__ __launch_bounds__(256) void zpad_x2_kernel(unsigned short* __restrict__ X2p) {
  const int b = blockIdx.x;
  unsigned short* Xb = X2p + (size_t)b * 65 * 65 * 128;
  for (int i = threadIdx.x; i < 129 * 128; i += 256) {
    const int j = i >> 7, ci = i & 127;
    size_t off;
    if (j < 65) off = ((size_t)64 * 65 + j) * 128 + ci;
    else off = ((size_t)(j - 65) * 65 + 64) * 128 + ci;
    Xb[off] = 0;
  }
}

// -------- weight repack: wt fp32 [256][128][3][3] -> Wtb2 bf16 coalesced ----
__global__ __launch_bounds__(256) void wtprep_kernel(const float* __restrict__ wt,
                                                     unsigned short* __restrict__ Wtb2) {
  const int i = blockIdx.x * 256 + threadIdx.x;
  if (i >= 9 * 256 * 128) return;
  const int e = i & 7, lane = (i >> 3) & 63, c4 = (i >> 9) & 3;
  const int cot = (i >> 11) & 15, tap = i >> 15;
  const int co = cot * 16 + (lane & 15);
  const int ci = c4 * 32 + (lane >> 4) * 8 + e;
  Wtb2[i] = f2bf(wt[((size_t)co * 128 + ci) * 9 + tap]);
}

// ------- convT: single-stage halo (1 barrier), fused Y IN-stats -------------
__global__ __launch_bounds__(256, 3) void convt_mfma_kernel(
    const unsigned short* __restrict__ X2p, const unsigned short* __restrict__ Wtb2,
    const float* __restrict__ bt, unsigned short* __restrict__ Y,
    float* __restrict__ ssumY, float* __restrict__ ssqY) {
  const int raw = blockIdx.x;
  const int swz = (raw & 7) * 256 + (raw >> 3);
  const int b = swz >> 8;
  const int rem = swz & 255;
  const int cls = rem >> 6;
  const int sy = rem & 63;
  const int py = cls & 1, px = cls >> 1;

  const int kyA = py ? 0 : 1, kxA = px ? 0 : 1;
  int tk[4], tdy[4], tdx[4];
  int ntaps = 0;
  tk[ntaps] = kyA * 3 + kxA; tdy[ntaps] = 0; tdx[ntaps] = 0; ++ntaps;
  if (px) { tk[ntaps] = kyA * 3 + 2; tdy[ntaps] = 0; tdx[ntaps] = 1; ++ntaps; }
  if (py) { tk[ntaps] = 6 + kxA; tdy[ntaps] = 1; tdx[ntaps] = 0; ++ntaps; }
  if (py && px) { tk[ntaps] = 8; tdy[ntaps] = 1; tdx[ntaps] = 1; ++ntaps; }

  __shared__ unsigned short As2[2080 * 8];  // 33.3 KB: 2 rows x 65 cols x 128ci

  const int t = threadIdx.x;
  const int lane = t & 63;
  const int wn = t >> 6;
  const int lg = lane >> 4, lr = lane & 15;
  const int co_w = wn * 64;

  const unsigned short* Xb = X2p + (size_t)b * 65 * 65 * 128;

  // stage all 2080 16B-slots: s = (r*65+c)*16 + hs; stored eighth g = hs^(c&7)
#pragma unroll
  for (int k = 0; k < 9; ++k) {
    int s;
    bool act = true;
    if (k < 8) s = k * 256 + t;
    else { s = 2048 + lane; act = (wn == 0 && lane < 32); }
    const int r = s >= 1040 ? 1 : 0;
    const int rm = s - r * 1040;
    const int c = rm >> 4, hs = rm & 15;
    const int g = hs ^ (c & 7);
    const unsigned short* gsrc = Xb + ((size_t)(sy + r) * 65 + c) * 128 + g * 8;
    unsigned short* ldst =
        As2 + (size_t)(k < 8 ? (k * 256 + wn * 64) : 2048) * 8;
    if (act) gload_lds16(gsrc, ldst);
  }

  f32x4 acc[4][4];
#pragma unroll
  for (int mt = 0; mt < 4; ++mt)
#pragma unroll
    for (int nt = 0; nt < 4; ++nt) {
      f32x4 z = {0.f, 0.f, 0.f, 0.f};
      acc[mt][nt] = z;
    }
  __syncthreads();

  const unsigned short* wlane = Wtb2 + (size_t)lane * 8;
  for (int c8 = 0; c8 < 4; ++c8) {
    for (int tp = 0; tp < ntaps; ++tp) {
      const int dy = tdy[tp], dx = tdx[tp];
      short8 af[4];
#pragma unroll
      for (int mt = 0; mt < 4; ++mt) {
        const int c = mt * 16 + lr + dx;
        const int hs = (c8 * 4 + lg) ^ (c & 7);
        af[mt] = *(const short8*)(As2 + (size_t)((dy * 65 + c) * 16 + hs) * 8);
      }
      const unsigned short* wt_ =
          wlane + (size_t)(((tk[tp] * 16 + wn * 4) * 4) + c8) * 512;
#pragma unroll
      for (int nt = 0; nt < 4; ++nt) {
        const short8 bf = *(const short8*)(wt_ + (size_t)nt * (4 * 512));
#pragma unroll
        for (int mt = 0; mt < 4; ++mt)
          acc[mt][nt] = __builtin_amdgcn_mfma_f32_16x16x32_bf16(
              af[mt], bf, acc[mt][nt], 0, 0, 0);
      }
    }
  }

  // epilogue: +bias, write Y px-major bf16, fused per-channel stats
  const int oy = 2 * sy + py;
  unsigned short* Yb = Y + ((size_t)b * 16384 + (size_t)oy * 128 + px) * 256;
  float bco[4], sS[4], sQ[4];
#pragma unroll
  for (int nt = 0; nt < 4; ++nt) {
    bco[nt] = bt[co_w + nt * 16 + lr];
    sS[nt] = 0.f;
    sQ[nt] = 0.f;
  }
#pragma unroll
  for (int mt = 0; mt < 4; ++mt) {
#pragma unroll
    for (int r = 0; r < 4; ++r) {
      const int sx = mt * 16 + lg * 4 + r;
      unsigned short* yp = Yb + (size_t)(2 * sx) * 256 + co_w + lr;
#pragma unroll
      for (int nt = 0; nt < 4; ++nt) {
        const float v = acc[mt][nt][r] + bco[nt];
        yp[nt * 16] = f2bf(v);
        sS[nt] += v;
        sQ[nt] += v * v;
      }
    }
  }
  // reduce over lg (lanes ^16, ^32); then lanes lg==0 hold per-co totals
#pragma unroll
  for (int nt = 0; nt < 4; ++nt) {
    sS[nt] += __shfl_xor(sS[nt], 16);
    sS[nt] += __shfl_xor(sS[nt], 32);
    sQ[nt] += __shfl_xor(sQ[nt], 16);
    sQ[nt] += __shfl_xor(sQ[nt], 32);
  }
  if (lg == 0) {
#pragma unroll
    for (int nt = 0; nt < 4; ++nt) {
      atomicAdd(&ssumY[b * 256 + co_w + nt * 16 + lr], sS[nt]);
      atomicAdd(&ssqY[b * 256 + co_w + nt * 16 + lr], sQ[nt]);
    }
  }
}

// ------- apply IN + LReLU to Y (short8), write bf16 into Xpad interior -------
__global__ __launch_bounds__(256) void inorm_apply_kernel(
    const unsigned short* __restrict__ Y, const float* __restrict__ ssum,
    const float* __restrict__ ssq, unsigned short* __restrict__ Xpad) {
  const int b = blockIdx.y, sl = blockIdx.x;
  const int t = threadIdx.x;
  const int rg = t >> 5;
  const int c0 = (t & 31) * 8;
  float m[8], r[8];
#pragma unroll
  for (int j = 0; j < 8; ++j) {
    const float mm = ssum[b * 256 + c0 + j] * (1.f / 16384.f);
    float var = ssq[b * 256 + c0 + j] * (1.f / 16384.f) - mm * mm;
    var = var < 0.f ? 0.f : var;
    m[j] = mm;
    r[j] = rsqrtf(var + 1e-5f);
  }
  const unsigned short* base = Y + ((size_t)b * 16384 + sl * 256) * 256;
  unsigned short* dstb = Xpad + (size_t)b * 130 * 130 * 256;
  for (int i = 0; i < 32; ++i) {
    const int row = sl * 256 + rg + i * 8;
    const int yy = row >> 7, xx = row & 127;
    union { short8 v; unsigned short u[8]; } pk;
    pk.v = *(const short8*)(base + (size_t)(rg + i * 8) * 256 + c0);
#pragma unroll
    for (int j = 0; j < 8; ++j) {
      float v = bf2f(pk.u[j]);
      v = (v - m[j]) * r[j];
      v = v >= 0.f ? v : 0.2f * v;
      pk.u[j] = f2bf(v);
    }
    *(short8*)(dstb + ((size_t)(yy + 1) * 130 + (xx + 1)) * 256 + c0) = pk.v;
  }
}

// ---------------- reflect borders of Xpad: rows then cols ----------------
__global__ __launch_bounds__(256) void pad_rows_kernel(unsigned short* __restrict__ Xp) {
  const int b = blockIdx.x >> 1, side = blockIdx.x & 1;
  unsigned short* Xb = Xp + (size_t)b * 130 * 130 * 256;
  const int dr = side ? 129 : 0, sr = side ? 127 : 2;
  for (int i = threadIdx.x; i < 4096; i += 256) {
    const int c = 1 + (i >> 5), o = (i & 31) * 8;
    *(short8*)(Xb + ((size_t)dr * 130 + c) * 256 + o) =
        *(const short8*)(Xb + ((size_t)sr * 130 + c) * 256 + o);
  }
}
__global__ __launch_bounds__(256) void pad_cols_kernel(unsigned short* __restrict__ Xp) {
  const int b = blockIdx.x >> 1, side = blockIdx.x & 1;
  unsigned short* Xb = Xp + (size_t)b * 130 * 130 * 256;
  const int dc = side ? 129 : 0, sc = side ? 127 : 2;
  for (int i = threadIdx.x; i < 130 * 32; i += 256) {
    const int r = i >> 5, o = (i & 31) * 8;
    *(short8*)(Xb + ((size_t)r * 130 + dc) * 256 + o) =
        *(const short8*)(Xb + ((size_t)r * 130 + sc) * 256 + o);
  }
}

// ------ weight repack: w3 fp32 [512][256][9] -> Wb2 bf16 coalesced ------
__global__ __launch_bounds__(256) void wprep_kernel(const float* __restrict__ w3,
                                                    unsigned short* __restrict__ Wb2) {
  const int i = blockIdx.x * 256 + threadIdx.x;
  if (i >= 9 * 512 * 256) return;
  const int e = i & 7, lane = (i >> 3) & 63, c8 = (i >> 9) & 7;
  const int cot = (i >> 12) & 31, tap = i >> 17;
  const int co = cot * 16 + (lane & 15);
  const int ci = c8 * 32 + (lane >> 4) * 8 + e;
  Wb2[i] = f2bf(w3[((size_t)co * 256 + ci) * 9 + tap]);
}

// ---------------- label extraction + counts from one-hot segmap ----------------
__global__ __launch_bounds__(256) void label_kernel(
    const float* __restrict__ segmap, int* __restrict__ labels,
    float* __restrict__ cnt) {
  const int b = blockIdx.y;
  const int p = blockIdx.x * 256 + threadIdx.x;
  const int i = p >> 7, j = p & 127;
  const float* sp = segmap + (size_t)b * 19 * 65536 + (2 * i) * 256 + 2 * j;
  int lab = 0;
#pragma unroll
  for (int s = 0; s < 19; ++s)
    if (sp[(size_t)s * 65536] != 0.f) lab = s;
  labels[b * 16384 + p] = lab;
  atomicAdd(&cnt[b * 19 + lab], 1.0f);
}

// ---------------- conv3: bf16 MFMA implicit GEMM + tanh + region pool --------
// R11/R14 structure, UNCHANGED (proven 612us).
__global__ __launch_bounds__(256, 3) void conv3_mfma_pool_kernel(
    const unsigned short* __restrict__ Xpad, const unsigned short* __restrict__ Wb2,
    const float* __restrict__ bias, const int* __restrict__ labels,
    float* __restrict__ sums) {
  const int raw = blockIdx.x;
  const int swz = (raw & 7) * 512 + (raw >> 3);
  const int b = swz >> 9;
  const int rem = swz & 511;
  const int y = rem >> 2;
  const int coq = rem & 3;

  constexpr int SLOTS = 1600;
  __shared__ unsigned short Asw[2 * SLOTS * 8];
  float* lsum = (float*)Asw;

  const int t = threadIdx.x;
  const int lane = t & 63;
  const int wave = t >> 6;
  const int wm = wave >> 1;
  const int wn = wave & 1;
  const int lg = lane >> 4, lr = lane & 15;
  const int co_w = coq * 128 + wn * 64;

  const unsigned short* Xb = Xpad + (size_t)b * 130 * 130 * 256;

  const unsigned short* sp[7];
  {
#pragma unroll
    for (int k = 0; k < 7; ++k) {
      int s;
      if (k < 6) s = t + k * 256;
      else s = (t < 24) ? (1536 + t) : 1536;
      const int r = s / 520, rm = s % 520, c = rm >> 2, hs = rm & 3;
      const int E = r * 130 + c;
      const int h = hs ^ ((E >> 1) & 3);
      sp[k] = Xb + ((size_t)(y + r) * 130 + c) * 256 + h * 8;
    }
  }

  f32x4 acc[4][4];
#pragma unroll
  for (int mt = 0; mt < 4; ++mt)
#pragma unroll
    for (int nt = 0; nt < 4; ++nt) {
      f32x4 z = {0.f, 0.f, 0.f, 0.f};
      acc[mt][nt] = z;
    }

  const unsigned short* wlane = Wb2 + (size_t)lane * 8;

  const int wslot = wave * 64;
#define STAGE(bufSel, off)                                                   \
  {                                                                          \
    unsigned short* base_ = Asw + (bufSel) * (SLOTS * 8);                    \
    gload_lds16(sp[0] + (off), base_ + (size_t)wslot * 8);                   \
    gload_lds16(sp[1] + (off), base_ + (size_t)(wslot + 256) * 8);           \
    gload_lds16(sp[2] + (off), base_ + (size_t)(wslot + 512) * 8);           \
    gload_lds16(sp[3] + (off), base_ + (size_t)(wslot + 768) * 8);           \
    gload_lds16(sp[4] + (off), base_ + (size_t)(wslot + 1024) * 8);          \
    gload_lds16(sp[5] + (off), base_ + (size_t)(wslot + 1280) * 8);          \
    if (wave == 0 && lane < 24)                                              \
      gload_lds16(sp[6] + (off), base_ + (size_t)1536 * 8);                  \
  }

  STAGE(0, 0)
  __syncthreads();

  for (int c8 = 0; c8 < 8; ++c8) {
    if (c8 < 7) STAGE((c8 + 1) & 1, (c8 + 1) * 32)
    const unsigned short* Ab = Asw + (c8 & 1) * (SLOTS * 8);
#pragma unroll
    for (int ky = 0; ky < 3; ++ky) {
#pragma unroll
      for (int kx = 0; kx < 3; ++kx) {
        const unsigned short* wt_ =
            wlane +
            (size_t)(((ky * 3 + kx) * 32 + coq * 8 + wn * 4) * 8 + c8) * 512;
        short8 bfv[4];
#pragma unroll
        for (int nt = 0; nt < 4; ++nt)
          bfv[nt] = *(const short8*)(wt_ + (size_t)nt * (8 * 512));
        short8 af[4];
#pragma unroll
        for (int mt = 0; mt < 4; ++mt) {
          const int E = ky * 130 + wm * 64 + mt * 16 + lr + kx;
          const int hh = lg ^ ((E >> 1) & 3);
          af[mt] = *(const short8*)(Ab + (size_t)E * 32 + hh * 8);
        }
#pragma unroll
        for (int nt = 0; nt < 4; ++nt) {
#pragma unroll
          for (int mt = 0; mt < 4; ++mt)
            acc[mt][nt] = __builtin_amdgcn_mfma_f32_16x16x32_bf16(
                af[mt], bfv[nt], acc[mt][nt], 0, 0, 0);
        }
      }
    }
    __syncthreads();
  }
#undef STAGE

  for (int i = t; i < 19 * 128; i += 256) lsum[i] = 0.f;
  __syncthreads();

  const int* labp = labels + b * 16384 + y * 128;
  float bco[4];
#pragma unroll
  for (int nt = 0; nt < 4; ++nt) bco[nt] = bias[co_w + nt * 16 + lr];
#pragma unroll
  for (int mt = 0; mt < 4; ++mt) {
#pragma unroll
    for (int r = 0; r < 4; ++r) {
      const int lab = labp[wm * 64 + mt * 16 + lg * 4 + r];
#pragma unroll
      for (int nt = 0; nt < 4; ++nt) {
        const float v = tanh_fast(acc[mt][nt][r] + bco[nt]);
        atomicAdd(&lsum[lab * 128 + wn * 64 + nt * 16 + lr], v);
      }
    }
  }
  __syncthreads();
  for (int i = t; i < 19 * 128; i += 256) {
    const float v = lsum[i];
    if (v != 0.f) {
      const int sI = i >> 7, c = i & 127;
      atomicAdd(&sums[((size_t)b * 19 + sI) * 512 + coq * 128 + c], v);
    }
  }
}

// ---------------- finalize: out = cnt>0 ? sums/max(cnt,1) : 0 ----------------
__global__ __launch_bounds__(256) void finalize_kernel(
    const float* __restrict__ sums, const float* __restrict__ cnt,
    float* __restrict__ out) {
  const int i = blockIdx.x * 256 + threadIdx.x;
  if (i >= B * 19 * 512) return;
  const int bs = i >> 9;
  const float c = cnt[bs];
  out[i] = c > 0.f ? sums[i] / fmaxf(c, 1.f) : 0.f;
}

// ---------------------------------------------------------------------------
extern "C" void kernel_launch(void* const* d_in, const int* in_sizes, int n_in,
                              void* d_out, int out_size, void* d_ws,
                              size_t ws_size, hipStream_t stream) {
  const float* input = (const float*)d_in[0];
  const float* segmap = (const float*)d_in[1];
  const float* w0 = (const float*)d_in[2];
  const float* b0 = (const float*)d_in[3];
  const float* w1 = (const float*)d_in[4];
  const float* b1 = (const float*)d_in[5];
  const float* w2 = (const float*)d_in[6];
  const float* b2 = (const float*)d_in[7];
  const float* wt = (const float*)d_in[8];
  const float* bt = (const float*)d_in[9];
  const float* w3 = (const float*)d_in[10];
  const float* b3 = (const float*)d_in[11];
  float* out = (float*)d_out;

  unsigned short* Xpad = (unsigned short*)d_ws;      // 34,611,200 us (69.2MB)
  unsigned short* X2p = Xpad + 34611200;             //  4,326,400 us
  unsigned short* Y = X2p + 4326400;                 // 33,554,432 us
  float* sums = (float*)(Y + 33554432);              //     77,824 f
  float* cnt = sums + 77824;                         //        152 f
  float* ssum0 = cnt + 152;                          //        256 f
  float* ssq0 = ssum0 + 256;                         //        256 f
  float* ssum1 = ssq0 + 256;                         //        512 f
  float* ssq1 = ssum1 + 512;                         //        512 f
  float* ssum2 = ssq1 + 512;                         //      1,024 f
  float* ssq2 = ssum2 + 1024;                        //      1,024 f
  float* ssumY = ssq2 + 1024;                        //      2,048 f
  float* ssqY = ssumY + 2048;                        //      2,048 f
  int* labels = (int*)(ssqY + 2048);                 //    131,072 i
  unsigned short* Wb2 = (unsigned short*)(labels + 131072);  // 1,179,648 us
  unsigned short* Wtb2 = Wb2 + 1179648;              //    294,912 us
  unsigned short* w1b = Wtb2 + 294912;               //     18,432 us
  unsigned short* w2b = w1b + 18432;                 //     73,728 us
  // Xp0/Xp1 overlay Y (dead until convt writes Y)
  unsigned short* Xp0 = Y;                           // 17,040,384 us
  unsigned short* Xp1 = Y + 17040384;                //  8,652,800 us

  hipMemsetAsync(sums, 0, (77824 + 152 + 7680) * sizeof(float), stream);

  wprep_kernel<<<dim3((9 * 512 * 256 + 255) / 256), 256, 0, stream>>>(w3, Wb2);
  wtprep_kernel<<<dim3((9 * 256 * 128 + 255) / 256), 256, 0, stream>>>(wt, Wtb2);
  w1prep_kernel<<<dim3((9 * 64 * 32 + 255) / 256), 256, 0, stream>>>(w1, w1b);
  w2prep_kernel<<<dim3((9 * 128 * 64 + 255) / 256), 256, 0, stream>>>(w2, w2b);

  conv0_kernel<<<dim3(256, B), 256, 0, stream>>>(input, w0, b0, Xp0);
  zpad0_kernel<<<dim3(B), 256, 0, stream>>>(Xp0);
  stats_px_kernel<32, 8, 258, 1, 16><<<dim3(64, B), 256, 0, stream>>>(Xp0, ssum0, ssq0);
  apply_px_kernel<32, 8, 258, 1><<<dim3(1024, B), 256, 0, stream>>>(Xp0, ssum0, ssq0);

  conv1_mfma_kernel<<<dim3(1024), 256, 0, stream>>>(Xp0, w1b, b1, Xp1);
  zpad1_kernel<<<dim3(B), 256, 0, stream>>>(Xp1);
  stats_px_kernel<64, 7, 130, 1, 16><<<dim3(32, B), 256, 0, stream>>>(Xp1, ssum1, ssq1);
  apply_px_kernel<64, 7, 130, 1><<<dim3(512, B), 256, 0, stream>>>(Xp1, ssum1, ssq1);

  conv2_mfma_kernel<<<dim3(512), 256, 0, stream>>>(Xp1, w2b, b2, X2p);
  zpad_x2_kernel<<<dim3(B), 256, 0, stream>>>(X2p);
  stats_px_kernel<128, 6, 65, 0, 16><<<dim3(16, B), 256, 0, stream>>>(X2p, ssum2, ssq2);
  apply_px_kernel<128, 6, 65, 0><<<dim3(256, B), 256, 0, stream>>>(X2p, ssum2, ssq2);

  convt_mfma_kernel<<<dim3(2048), 256, 0, stream>>>(X2p, Wtb2, bt, Y, ssumY, ssqY);
  inorm_apply_kernel<<<dim3(64, B), 256, 0, stream>>>(Y, ssumY, ssqY, Xpad);
  pad_rows_kernel<<<dim3(2 * B), 256, 0, stream>>>(Xpad);
  pad_cols_kernel<<<dim3(2 * B), 256, 0, stream>>>(Xpad);
  label_kernel<<<dim3(64, B), 256, 0, stream>>>(segmap, labels, cnt);
  conv3_mfma_pool_kernel<<<dim3(4096), 256, 0, stream>>>(Xpad, Wb2, b3, labels, sums);
  finalize_kernel<<<dim3((B * 19 * 512 + 255) / 256), 256, 0, stream>>>(sums, cnt, out);
}